// Round 1
// 541.572 us; speedup vs baseline: 1.3032x; 1.3032x over previous
//
#include <hip/hip_runtime.h>
#include <hip/hip_bf16.h>
#include <math.h>

typedef unsigned int u32;
typedef unsigned short u16;

typedef __bf16 bf16_t;
typedef bf16_t bf16x8 __attribute__((ext_vector_type(8)));
typedef float f32x4 __attribute__((ext_vector_type(4)));

#define EPSF 1e-8f

__device__ __forceinline__ float bf2f(u16 h) {
    union { u32 u; float f; } v; v.u = ((u32)h) << 16; return v.f;
}
__device__ __forceinline__ u16 f2bf(float f) {
    union { float ff; u32 u; } v; v.ff = f;
    u32 u = v.u;
    return (u16)((u + 0x7fffu + ((u >> 16) & 1u)) >> 16);
}
__device__ __forceinline__ float gelu_exact(float v) {
    return 0.5f * v * (1.0f + erff(v * 0.70710678118654752440f));
}
__device__ __forceinline__ void gld_lds16(const void* g, void* l) {
    __builtin_amdgcn_global_load_lds(
        (const __attribute__((address_space(1))) unsigned int*)g,
        (__attribute__((address_space(3))) unsigned int*)l, 16, 0, 0);
}

// ---------------- K1: conv (fp32, registers) + MFMA pointwise + wave-local RMS + GELU ----------------
// Block: 32 L-positions, 256 threads. Conv writes H[4][32][256] bf16 (XOR-swizzled 8-ch groups)
// into 64 KB LDS. Then wave s GEMMs its scale: M=32 x N=128 x K=256, A from LDS, B from
// L2-cached packed bf16 weights. RMS is wave-local (in-reg + shfl_xor over 16 col-lanes).
template<int S>
__device__ __forceinline__ void conv_scale(
    const float* __restrict__ dw, const float* xc, u16* __restrict__ H, int c)
{
    const int K = 2 * S + 1;
    float d[K];
    #pragma unroll
    for (int j = 0; j < K; j++) d[j] = dw[c * K + j];
    const int chunk = c & ~31;
    const int q = (c >> 3) & 3;
    const int jj = c & 7;
    #pragma unroll
    for (int l = 0; l < 32; l++) {
        float a = 0.f;
        #pragma unroll
        for (int j = 0; j < K; j++) a += xc[l + 3 - S + j] * d[j];
        H[(S * 32 + l) * 256 + chunk + ((q ^ ((l >> 1) & 3)) << 3) + jj] = f2bf(a);
    }
}

__global__ __launch_bounds__(256) void k_feats(
    const float* __restrict__ x,
    const float* __restrict__ dw1, const float* __restrict__ dw3,
    const float* __restrict__ dw5, const float* __restrict__ dw7,
    const float* __restrict__ cn1, const float* __restrict__ cn3,
    const float* __restrict__ cn5, const float* __restrict__ cn7,
    const u16* __restrict__ pwb,
    u32* __restrict__ feats32)
{
    __shared__ __align__(16) u16 H[4 * 32 * 256];   // 64 KB; bounce-buffer overlay later
    const int t = threadIdx.x;
    const int lane = t & 63;
    const int wave = t >> 6;
    const int l0 = blockIdx.x * 32;
    const int b = blockIdx.y;
    const float* xb = x + (size_t)b * 4096 * 256;

    // x column (lane = channel) in registers, fp32
    float xc[38];
    #pragma unroll
    for (int r = 0; r < 38; r++) {
        int g = l0 - 3 + r;
        xc[r] = (g >= 0 && g < 4096) ? xb[(size_t)g * 256 + t] : 0.0f;
    }
    conv_scale<0>(dw1, xc, H, t);
    conv_scale<1>(dw3, xc, H, t);
    conv_scale<2>(dw5, xc, H, t);
    conv_scale<3>(dw7, xc, H, t);
    __syncthreads();

    // ---- per-wave GEMM: scale s = wave ----
    const int s = wave;
    const u16* wB = pwb + (size_t)s * 32768;   // [128][256] bf16
    const int col = lane & 15;
    const int q = lane >> 4;

    f32x4 acc[2][8];
    #pragma unroll
    for (int mt = 0; mt < 2; mt++)
        #pragma unroll
        for (int nt = 0; nt < 8; nt++) acc[mt][nt] = f32x4{0.f, 0.f, 0.f, 0.f};

    int a_off[2];
    #pragma unroll
    for (int mt = 0; mt < 2; mt++) {
        int m = mt * 16 + col;
        a_off[mt] = (s * 32 + m) * 256 + ((q ^ ((m >> 1) & 3)) << 3);
    }

    #pragma unroll 2
    for (int kt = 0; kt < 8; kt++) {
        bf16x8 af0 = *(const bf16x8*)&H[a_off[0] + kt * 32];
        bf16x8 af1 = *(const bf16x8*)&H[a_off[1] + kt * 32];
        #pragma unroll
        for (int nt = 0; nt < 8; nt++) {
            bf16x8 bfv = *(const bf16x8*)&wB[(nt * 16 + col) * 256 + kt * 32 + q * 8];
            acc[0][nt] = __builtin_amdgcn_mfma_f32_16x16x32_bf16(af0, bfv, acc[0][nt], 0, 0, 0);
            acc[1][nt] = __builtin_amdgcn_mfma_f32_16x16x32_bf16(af1, bfv, acc[1][nt], 0, 0, 0);
        }
    }

    // ---- wave-local RMS over the 128 channels of this scale ----
    float rinv_[2][4];
    #pragma unroll
    for (int mt = 0; mt < 2; mt++)
        #pragma unroll
        for (int r = 0; r < 4; r++) {
            float ss = 0.f;
            #pragma unroll
            for (int nt = 0; nt < 8; nt++) ss += acc[mt][nt][r] * acc[mt][nt][r];
            ss += __shfl_xor(ss, 1);
            ss += __shfl_xor(ss, 2);
            ss += __shfl_xor(ss, 4);
            ss += __shfl_xor(ss, 8);
            rinv_[mt][r] = 1.0f / (sqrtf(ss * (1.0f / 128.0f)) + EPSF);
        }

    const float* cn = (s == 0) ? cn1 : (s == 1) ? cn3 : (s == 2) ? cn5 : cn7;
    float cnv[8];
    #pragma unroll
    for (int nt = 0; nt < 8; nt++) cnv[nt] = cn[nt * 16 + col];

    __syncthreads();   // all GEMM reads of H complete before bounce overlay

    u16* bounce = H + s * 8192;   // [32][136] u16 region, overlays this wave's H slice
    #pragma unroll
    for (int mt = 0; mt < 2; mt++)
        #pragma unroll
        for (int nt = 0; nt < 8; nt++)
            #pragma unroll
            for (int r = 0; r < 4; r++) {
                int m = mt * 16 + q * 4 + r;
                float g = gelu_exact(acc[mt][nt][r] * rinv_[mt][r] * cnv[nt]);
                bounce[m * 136 + nt * 16 + col] = f2bf(g);
            }
    __syncthreads();

    // coalesced store: 64 lanes = 64 u32 (128 bf16 ch) per position
    const u32* b32 = (const u32*)bounce;
    size_t row0 = (size_t)b * 4096 + l0;
    #pragma unroll 4
    for (int m = 0; m < 32; m++)
        feats32[(row0 + m) * 256 + s * 64 + lane] = b32[m * 68 + lane];
}

// ---------------- K2: attention MLP (MFMA) + softmax + IN-PLACE feats scaling ----------------
// Block = 64 rows, 256 threads (4 waves). feats tile [64][512] bf16 staged to LDS via
// global_load_lds with XOR-pre-swizzled source (16B-unit u stored at u^(row&15)), so the
// MFMA ds_read_b128 A-fragments are conflict-free. GEMM1: M=64 N=128 K=512, waves split N
// (32 each). b1+gelu in registers; GEMM2 (w2, N=4) as in-register dot + shfl_xor reduce;
// softmax per row; scale + coalesced store back from LDS.
__global__ __launch_bounds__(256) void k_attn(
    u16* __restrict__ feats, const u16* __restrict__ w1b,
    const float* __restrict__ b1,
    const float* __restrict__ w2, const float* __restrict__ b2)
{
    __shared__ __align__(16) u16 Fs[64 * 512];   // 64 KB, swizzled
    __shared__ float part[4][64][4];
    __shared__ float att4[64][4];
    const int t = threadIdx.x;
    const int lane = t & 63;
    const int wave = t >> 6;
    const size_t n0 = (size_t)blockIdx.x * 64;
    u16* fr = feats + n0 * 512;

    // ---- stage feats[64][512] -> LDS (linear dest, swizzled source) ----
    #pragma unroll
    for (int it = 0; it < 16; it++) {
        const int r = it * 4 + wave;             // wave-uniform row
        const int su = lane ^ (r & 15);          // source 16B-unit
        gld_lds16(fr + (size_t)r * 512 + su * 8, &Fs[r * 512]);
    }
    __syncthreads();

    // ---- GEMM1: acc[mt][nt] = feats[64,512] @ w1[128,512]^T, wave n-range = wave*32 ----
    const int col = lane & 15;
    const int q = lane >> 4;
    const u16* wB = w1b + (size_t)(wave * 32) * 512;

    f32x4 acc[4][2];
    #pragma unroll
    for (int mt = 0; mt < 4; mt++) {
        acc[mt][0] = f32x4{0.f, 0.f, 0.f, 0.f};
        acc[mt][1] = f32x4{0.f, 0.f, 0.f, 0.f};
    }

    #pragma unroll 2
    for (int kt = 0; kt < 16; kt++) {
        bf16x8 bf0 = *(const bf16x8*)&wB[(size_t)(0 * 16 + col) * 512 + kt * 32 + q * 8];
        bf16x8 bf1 = *(const bf16x8*)&wB[(size_t)(1 * 16 + col) * 512 + kt * 32 + q * 8];
        #pragma unroll
        for (int mt = 0; mt < 4; mt++) {
            const int m = mt * 16 + col;
            bf16x8 av = *(const bf16x8*)&Fs[m * 512 + (((kt * 4 + q) ^ col) * 8)];
            acc[mt][0] = __builtin_amdgcn_mfma_f32_16x16x32_bf16(av, bf0, acc[mt][0], 0, 0, 0);
            acc[mt][1] = __builtin_amdgcn_mfma_f32_16x16x32_bf16(av, bf1, acc[mt][1], 0, 0, 0);
        }
    }

    // ---- bias + gelu in registers ----
    float b1v[2];
    b1v[0] = b1[wave * 32 + col];
    b1v[1] = b1[wave * 32 + 16 + col];
    #pragma unroll
    for (int mt = 0; mt < 4; mt++)
        #pragma unroll
        for (int nt = 0; nt < 2; nt++)
            #pragma unroll
            for (int r = 0; r < 4; r++)
                acc[mt][nt][r] = gelu_exact(acc[mt][nt][r] + b1v[nt]);

    // ---- GEMM2 partials: p[s] = sum_n a1[m][n]*w2[s][n] over this wave's 32 n ----
    float w2v[4][2];
    #pragma unroll
    for (int s = 0; s < 4; s++) {
        w2v[s][0] = w2[s * 128 + wave * 32 + col];
        w2v[s][1] = w2[s * 128 + wave * 32 + 16 + col];
    }
    #pragma unroll
    for (int mt = 0; mt < 4; mt++)
        #pragma unroll
        for (int r = 0; r < 4; r++) {
            float g0 = acc[mt][0][r], g1 = acc[mt][1][r];
            float p0 = g0 * w2v[0][0] + g1 * w2v[0][1];
            float p1 = g0 * w2v[1][0] + g1 * w2v[1][1];
            float p2 = g0 * w2v[2][0] + g1 * w2v[2][1];
            float p3 = g0 * w2v[3][0] + g1 * w2v[3][1];
            #pragma unroll
            for (int msk = 1; msk < 16; msk <<= 1) {
                p0 += __shfl_xor(p0, msk);
                p1 += __shfl_xor(p1, msk);
                p2 += __shfl_xor(p2, msk);
                p3 += __shfl_xor(p3, msk);
            }
            if (col == 0) {
                const int m = mt * 16 + q * 4 + r;
                part[wave][m][0] = p0; part[wave][m][1] = p1;
                part[wave][m][2] = p2; part[wave][m][3] = p3;
            }
        }
    __syncthreads();

    // ---- cross-wave reduce + softmax (thread t -> row t>>2, scale t&3) ----
    {
        const int row = t >> 2, s = t & 3;
        float tot = part[0][row][s] + part[1][row][s] + part[2][row][s] + part[3][row][s] + b2[s];
        float mx = fmaxf(tot, __shfl_xor(tot, 1));
        mx = fmaxf(mx, __shfl_xor(mx, 2));
        float e = expf(tot - mx);
        float sum = e + __shfl_xor(e, 1);
        sum += __shfl_xor(sum, 2);
        att4[row][s] = e / sum;
    }
    __syncthreads();

    // ---- scale feats by att and store (coalesced: lane = 16B unit) ----
    #pragma unroll
    for (int it = 0; it < 16; it++) {
        const int r = it * 4 + wave;
        const int su = lane ^ (r & 15);          // LDS unit holding source unit `lane`
        const u16* src = &Fs[r * 512 + su * 8];
        const float a = att4[r][lane >> 4];      // unit covers ch lane*8.. -> scale lane>>4
        u32 o[4];
        #pragma unroll
        for (int j = 0; j < 4; j++) {
            u16 lo = src[2 * j], hi = src[2 * j + 1];
            o[j] = (u32)f2bf(bf2f(lo) * a) | ((u32)f2bf(bf2f(hi) * a) << 16);
        }
        *(uint4*)(fr + (size_t)r * 512 + lane * 8) = make_uint4(o[0], o[1], o[2], o[3]);
    }
}

// ---------------- K2b: pack final_w || res_w into bf16 [512][768] ----------------
__global__ __launch_bounds__(256) void k_packw(
    const float* __restrict__ fw, const float* __restrict__ rw, u16* __restrict__ wb)
{
    const int n = blockIdx.x;
    const int k = blockIdx.y * 256 + threadIdx.x;
    float v = (k < 512) ? fw[(size_t)n * 512 + k] : rw[(size_t)n * 256 + (k - 512)];
    wb[(size_t)n * 768 + k] = f2bf(v);
}

// ---------------- K2c: pack pw1/3/5/7 into bf16 [4][128][256] ----------------
__global__ __launch_bounds__(256) void k_packpw(
    const float* __restrict__ pw1, const float* __restrict__ pw3,
    const float* __restrict__ pw5, const float* __restrict__ pw7,
    u16* __restrict__ pwb)
{
    const int s = blockIdx.y;
    const float* pw = (s == 0) ? pw1 : (s == 1) ? pw3 : (s == 2) ? pw5 : pw7;
    const int i = blockIdx.x * 256 + threadIdx.x;
    pwb[(size_t)s * 32768 + i] = f2bf(pw[i]);
}

// ---------------- K2d: pack attn_w1 into bf16 [128][512] (overlays pwb after k_feats) ----
__global__ __launch_bounds__(256) void k_packw1(
    const float* __restrict__ w1, u16* __restrict__ w1b)
{
    const int i = blockIdx.x * 256 + threadIdx.x;
    w1b[i] = f2bf(w1[i]);
}

// ---------------- K3: MFMA GEMM — out[65536,512] = A[65536,768] * W[512,768]^T ----------------
__global__ __launch_bounds__(256) void k_final_mfma(
    const u16* __restrict__ feats, const float* __restrict__ x,
    const u16* __restrict__ wb, float* __restrict__ out)
{
    __shared__ __align__(16) u16 As[128 * 32];
    __shared__ __align__(16) u16 Bs[128 * 32];
    const int t = threadIdx.x;
    const int lane = t & 63;
    const int wave = t >> 6;
    const int m0 = blockIdx.x * 128;
    const int n0 = blockIdx.y * 128;

    const int srow_b = wave * 32 + (lane >> 2);
    const int sgp = lane & 3;

    f32x4 acc[4][4];
    #pragma unroll
    for (int i = 0; i < 4; i++)
        #pragma unroll
        for (int j = 0; j < 4; j++) acc[i][j] = f32x4{0.f, 0.f, 0.f, 0.f};

    const int wm = (wave & 1) * 64;
    const int wn = (wave >> 1) * 64;
    int a_off[4], b_off[4];
    #pragma unroll
    for (int i = 0; i < 4; i++) {
        int ra = wm + i * 16 + (lane & 15);
        a_off[i] = ra * 32 + (((lane >> 4) ^ ((ra >> 1) & 3)) * 8);
        int rb = wn + i * 16 + (lane & 15);
        b_off[i] = rb * 32 + (((lane >> 4) ^ ((rb >> 1) & 3)) * 8);
    }

    for (int kt = 0; kt < 24; ++kt) {
        const int k0 = kt * 32;
        #pragma unroll
        for (int j = 0; j < 2; j++) {
            int r = srow_b + j * 16;
            int g = sgp ^ ((r >> 1) & 3);
            gld_lds16(wb + (size_t)(n0 + r) * 768 + k0 + g * 8,
                      &Bs[wave * 1024 + j * 512]);
        }
        if (kt < 16) {
            #pragma unroll
            for (int j = 0; j < 2; j++) {
                int r = srow_b + j * 16;
                int g = sgp ^ ((r >> 1) & 3);
                gld_lds16(feats + (size_t)(m0 + r) * 512 + k0 + g * 8,
                          &As[wave * 1024 + j * 512]);
            }
        } else {
            const int kx0 = (kt - 16) * 32;
            const int row = t >> 1;
            #pragma unroll
            for (int h = 0; h < 2; h++) {
                int g2 = (t & 1) * 2 + h;
                const float4* xp = (const float4*)(x + (size_t)(m0 + row) * 256 + kx0 + g2 * 8);
                float4 v0 = xp[0], v1 = xp[1];
                u32 p0 = (u32)f2bf(v0.x) | ((u32)f2bf(v0.y) << 16);
                u32 p1 = (u32)f2bf(v0.z) | ((u32)f2bf(v0.w) << 16);
                u32 p2 = (u32)f2bf(v1.x) | ((u32)f2bf(v1.y) << 16);
                u32 p3 = (u32)f2bf(v1.z) | ((u32)f2bf(v1.w) << 16);
                int gp = g2 ^ ((row >> 1) & 3);
                *(uint4*)&As[row * 32 + gp * 8] = make_uint4(p0, p1, p2, p3);
            }
        }
        __syncthreads();
        bf16x8 af[4], bfr[4];
        #pragma unroll
        for (int i = 0; i < 4; i++) af[i] = *(const bf16x8*)&As[a_off[i]];
        #pragma unroll
        for (int i = 0; i < 4; i++) bfr[i] = *(const bf16x8*)&Bs[b_off[i]];
        #pragma unroll
        for (int mi = 0; mi < 4; mi++)
            #pragma unroll
            for (int ni = 0; ni < 4; ni++)
                acc[mi][ni] = __builtin_amdgcn_mfma_f32_16x16x32_bf16(
                    af[mi], bfr[ni], acc[mi][ni], 0, 0, 0);
        __syncthreads();
    }

    const int cn = n0 + wn + (lane & 15);
    const int rm = m0 + wm + (lane >> 4) * 4;
    #pragma unroll
    for (int mi = 0; mi < 4; mi++)
        #pragma unroll
        for (int ni = 0; ni < 4; ni++)
            #pragma unroll
            for (int r = 0; r < 4; r++)
                out[(size_t)(rm + mi * 16 + r) * 512 + cn + ni * 16] = acc[mi][ni][r];
}

// ---------------- K4: in-place row RMSNorm over 512 ----------------
__global__ __launch_bounds__(256) void k_norm(
    float* __restrict__ out, const float* __restrict__ nsc)
{
    __shared__ float part[2][2];
    const int t = threadIdx.x;
    const int r = t >> 7;
    const int cc = (t & 127) * 4;
    const size_t row = (size_t)blockIdx.x * 2 + r;
    float4 v = *(float4*)&out[row * 512 + cc];
    float ss = v.x * v.x + v.y * v.y + v.z * v.z + v.w * v.w;
    #pragma unroll
    for (int m = 1; m < 64; m <<= 1) ss += __shfl_xor(ss, m);
    if ((t & 63) == 0) part[r][(t >> 6) & 1] = ss;
    __syncthreads();
    float tot = part[r][0] + part[r][1];
    float rv = 1.0f / (sqrtf(tot * (1.0f / 512.0f)) + EPSF);
    const float4 s4 = *(const float4*)&nsc[cc];
    v.x *= rv * s4.x; v.y *= rv * s4.y; v.z *= rv * s4.z; v.w *= rv * s4.w;
    *(float4*)&out[row * 512 + cc] = v;
}

extern "C" void kernel_launch(void* const* d_in, const int* in_sizes, int n_in,
                              void* d_out, int out_size, void* d_ws, size_t ws_size,
                              hipStream_t stream)
{
    const float* x   = (const float*)d_in[0];
    const float* dw1 = (const float*)d_in[1];
    const float* pw1 = (const float*)d_in[2];
    const float* cn1 = (const float*)d_in[3];
    const float* dw3 = (const float*)d_in[4];
    const float* pw3 = (const float*)d_in[5];
    const float* cn3 = (const float*)d_in[6];
    const float* dw5 = (const float*)d_in[7];
    const float* pw5 = (const float*)d_in[8];
    const float* cn5 = (const float*)d_in[9];
    const float* dw7 = (const float*)d_in[10];
    const float* pw7 = (const float*)d_in[11];
    const float* cn7 = (const float*)d_in[12];
    const float* w1  = (const float*)d_in[13];
    const float* b1  = (const float*)d_in[14];
    const float* w2  = (const float*)d_in[15];
    const float* b2  = (const float*)d_in[16];
    const float* fw  = (const float*)d_in[17];
    const float* nsc = (const float*)d_in[18];
    const float* rw  = (const float*)d_in[19];

    // ws: feats bf16 [65536][512] @0 (64MB) | wb bf16 [512][768] @64MB (768KB) | pwb bf16 [4][128][256] (256KB)
    // w1b bf16 [128][512] (128KB) OVERLAYS pwb (pwb is dead after k_feats; w1b packed after it)
    u16* feats = (u16*)d_ws;
    u16* wbp   = (u16*)((char*)d_ws + (size_t)67108864);
    u16* pwb   = (u16*)((char*)d_ws + (size_t)67895296);
    u16* w1b   = pwb;
    float* out = (float*)d_out;
    if (ws_size < (size_t)68157440) return;  // loud failure if scratch too small

    k_packw<<<dim3(512, 3), 256, 0, stream>>>(fw, rw, wbp);
    k_packpw<<<dim3(128, 4), 256, 0, stream>>>(pw1, pw3, pw5, pw7, pwb);
    k_feats<<<dim3(128, 16), 256, 0, stream>>>(x, dw1, dw3, dw5, dw7,
                                               cn1, cn3, cn5, cn7, pwb, (u32*)feats);
    k_packw1<<<dim3(256), 256, 0, stream>>>(w1, w1b);
    k_attn<<<dim3(1024), 256, 0, stream>>>(feats, w1b, b1, w2, b2);
    k_final_mfma<<<dim3(512, 4), 256, 0, stream>>>(feats, x, wbp, out);
    k_norm<<<dim3(32768), 256, 0, stream>>>(out, nsc);
}

// Round 2
// 524.006 us; speedup vs baseline: 1.3469x; 1.0335x over previous
//
#include <hip/hip_runtime.h>
#include <hip/hip_bf16.h>
#include <math.h>

typedef unsigned int u32;
typedef unsigned short u16;

typedef __bf16 bf16_t;
typedef bf16_t bf16x8 __attribute__((ext_vector_type(8)));
typedef float f32x4 __attribute__((ext_vector_type(4)));

#define EPSF 1e-8f

__device__ __forceinline__ float bf2f(u16 h) {
    union { u32 u; float f; } v; v.u = ((u32)h) << 16; return v.f;
}
__device__ __forceinline__ u16 f2bf(float f) {
    union { float ff; u32 u; } v; v.ff = f;
    u32 u = v.u;
    return (u16)((u + 0x7fffu + ((u >> 16) & 1u)) >> 16);
}
__device__ __forceinline__ float gelu_exact(float v) {
    return 0.5f * v * (1.0f + erff(v * 0.70710678118654752440f));
}
__device__ __forceinline__ void gld_lds16(const void* g, void* l) {
    __builtin_amdgcn_global_load_lds(
        (const __attribute__((address_space(1))) unsigned int*)g,
        (__attribute__((address_space(3))) unsigned int*)l, 16, 0, 0);
}

// ---------------- K1 (fused): conv + MFMA pointwise + RMS + GELU + attention MLP + scale ----
// Block: 16 L-positions, 256 threads (4 waves). Conv writes H[4][16][256] bf16 into 32 KB LDS
// with 8-group XOR swizzle (ch-group g stored at g^(l&7) within 64-ch superchunk) so
// ds_read_b128 A-fragments hit the 32-bank floor. Wave s GEMMs scale s (M=16,N=128,K=256),
// wave-local RMS + gelu -> F[16][520] bf16 (overlays H). Then attention: GEMM1 M=16,N=128
// (waves split N, 32 each) from F + bf16 w1 (in d_out scratch), gelu, w2 dot + shfl reduce,
// softmax, scale F, coalesced uint4 store of final scaled feats.
template<int S>
__device__ __forceinline__ void conv_scale16(
    const float* __restrict__ dw, const float* xc, u16* __restrict__ H, int c)
{
    const int K = 2 * S + 1;
    float d[K];
    #pragma unroll
    for (int j = 0; j < K; j++) d[j] = dw[c * K + j];
    const int chunk = c & ~63;
    const int q6 = (c >> 3) & 7;
    const int jj = c & 7;
    #pragma unroll
    for (int l = 0; l < 16; l++) {
        float a = 0.f;
        #pragma unroll
        for (int j = 0; j < K; j++) a += xc[l + 3 - S + j] * d[j];
        H[(S * 16 + l) * 256 + chunk + ((q6 ^ (l & 7)) << 3) + jj] = f2bf(a);
    }
}

__global__ __launch_bounds__(256) void k_feats(
    const float* __restrict__ x,
    const float* __restrict__ dw1, const float* __restrict__ dw3,
    const float* __restrict__ dw5, const float* __restrict__ dw7,
    const float* __restrict__ cn1, const float* __restrict__ cn3,
    const float* __restrict__ cn5, const float* __restrict__ cn7,
    const u16* __restrict__ pwb, const u16* __restrict__ w1b,
    const float* __restrict__ b1, const float* __restrict__ w2,
    const float* __restrict__ b2,
    u32* __restrict__ feats32)
{
    __shared__ __align__(16) u16 H[4 * 16 * 256];   // 32 KB; F[16][520] overlays after scale GEMM
    __shared__ float part[4][16][4];
    __shared__ float att4[16][4];
    const int t = threadIdx.x;
    const int lane = t & 63;
    const int wave = t >> 6;
    const int c15 = lane & 15;
    const int q = lane >> 4;
    const int l0 = blockIdx.x * 16;
    const int b = blockIdx.y;
    const float* xb = x + (size_t)b * 4096 * 256;

    // x column (lane = channel) in registers, fp32
    float xc[22];
    #pragma unroll
    for (int r = 0; r < 22; r++) {
        int g = l0 - 3 + r;
        xc[r] = (g >= 0 && g < 4096) ? xb[(size_t)g * 256 + t] : 0.0f;
    }
    conv_scale16<0>(dw1, xc, H, t);
    conv_scale16<1>(dw3, xc, H, t);
    conv_scale16<2>(dw5, xc, H, t);
    conv_scale16<3>(dw7, xc, H, t);
    __syncthreads();

    // ---- per-wave scale GEMM: scale s = wave, M=16 x N=128 x K=256 ----
    const int s = wave;
    const u16* wB = pwb + (size_t)s * 32768;   // [128][256] bf16
    f32x4 acc[8];
    #pragma unroll
    for (int nt = 0; nt < 8; nt++) acc[nt] = f32x4{0.f, 0.f, 0.f, 0.f};

    const int row_base = (s * 16 + c15) * 256;
    const int m7 = c15 & 7;
    #pragma unroll 2
    for (int kt = 0; kt < 8; kt++) {
        const int g7 = (((kt & 1) << 2) | q) ^ m7;
        bf16x8 af = *(const bf16x8*)&H[row_base + ((kt >> 1) << 6) + (g7 << 3)];
        #pragma unroll
        for (int nt = 0; nt < 8; nt++) {
            bf16x8 bv = *(const bf16x8*)&wB[(nt * 16 + c15) * 256 + kt * 32 + q * 8];
            acc[nt] = __builtin_amdgcn_mfma_f32_16x16x32_bf16(af, bv, acc[nt], 0, 0, 0);
        }
    }

    // ---- wave-local RMS over the 128 channels of this scale (rows m = q*4+r) ----
    float rinv_[4];
    #pragma unroll
    for (int r = 0; r < 4; r++) {
        float ss = 0.f;
        #pragma unroll
        for (int nt = 0; nt < 8; nt++) ss += acc[nt][r] * acc[nt][r];
        ss += __shfl_xor(ss, 1);
        ss += __shfl_xor(ss, 2);
        ss += __shfl_xor(ss, 4);
        ss += __shfl_xor(ss, 8);
        rinv_[r] = 1.0f / (sqrtf(ss * (1.0f / 128.0f)) + EPSF);
    }

    const float* cn = (s == 0) ? cn1 : (s == 1) ? cn3 : (s == 2) ? cn5 : cn7;
    float cnv[8];
    #pragma unroll
    for (int nt = 0; nt < 8; nt++) cnv[nt] = cn[nt * 16 + c15];

    __syncthreads();   // all GEMM reads of H complete before F overlay

    u16* F = H;        // [16][520] bf16 feats tile (row stride 520 u16, 16B-aligned rows)
    #pragma unroll
    for (int nt = 0; nt < 8; nt++)
        #pragma unroll
        for (int r = 0; r < 4; r++) {
            const int m = q * 4 + r;
            float g = gelu_exact(acc[nt][r] * rinv_[r] * cnv[nt]);
            F[m * 520 + s * 128 + nt * 16 + c15] = f2bf(g);
        }
    __syncthreads();

    // ---- attention GEMM1: a1 = F[16,512] @ w1[128,512]^T, wave covers o in [wave*32, wave*32+32) ----
    f32x4 a1[2];
    a1[0] = f32x4{0.f, 0.f, 0.f, 0.f};
    a1[1] = f32x4{0.f, 0.f, 0.f, 0.f};
    #pragma unroll 4
    for (int kt = 0; kt < 16; kt++) {
        bf16x8 av = *(const bf16x8*)&F[c15 * 520 + kt * 32 + q * 8];
        bf16x8 bv0 = *(const bf16x8*)&w1b[(size_t)(wave * 32 + c15) * 512 + kt * 32 + q * 8];
        bf16x8 bv1 = *(const bf16x8*)&w1b[(size_t)(wave * 32 + 16 + c15) * 512 + kt * 32 + q * 8];
        a1[0] = __builtin_amdgcn_mfma_f32_16x16x32_bf16(av, bv0, a1[0], 0, 0, 0);
        a1[1] = __builtin_amdgcn_mfma_f32_16x16x32_bf16(av, bv1, a1[1], 0, 0, 0);
    }
    {
        const float b1v0 = b1[wave * 32 + c15];
        const float b1v1 = b1[wave * 32 + 16 + c15];
        #pragma unroll
        for (int r = 0; r < 4; r++) {
            a1[0][r] = gelu_exact(a1[0][r] + b1v0);
            a1[1][r] = gelu_exact(a1[1][r] + b1v1);
        }
    }

    // ---- GEMM2 partials over this wave's 32 o-channels + cross-wave softmax ----
    float w2v[4][2];
    #pragma unroll
    for (int sc = 0; sc < 4; sc++) {
        w2v[sc][0] = w2[sc * 128 + wave * 32 + c15];
        w2v[sc][1] = w2[sc * 128 + wave * 32 + 16 + c15];
    }
    #pragma unroll
    for (int r = 0; r < 4; r++) {
        float g0 = a1[0][r], g1 = a1[1][r];
        float p0 = g0 * w2v[0][0] + g1 * w2v[0][1];
        float p1 = g0 * w2v[1][0] + g1 * w2v[1][1];
        float p2 = g0 * w2v[2][0] + g1 * w2v[2][1];
        float p3 = g0 * w2v[3][0] + g1 * w2v[3][1];
        #pragma unroll
        for (int msk = 1; msk < 16; msk <<= 1) {
            p0 += __shfl_xor(p0, msk);
            p1 += __shfl_xor(p1, msk);
            p2 += __shfl_xor(p2, msk);
            p3 += __shfl_xor(p3, msk);
        }
        if (c15 == 0) {
            const int m = q * 4 + r;
            part[wave][m][0] = p0; part[wave][m][1] = p1;
            part[wave][m][2] = p2; part[wave][m][3] = p3;
        }
    }
    __syncthreads();

    if (t < 64) {
        const int m = t >> 2, sc = t & 3;
        float tot = part[0][m][sc] + part[1][m][sc] + part[2][m][sc] + part[3][m][sc] + b2[sc];
        float mx = fmaxf(tot, __shfl_xor(tot, 1));
        mx = fmaxf(mx, __shfl_xor(mx, 2));
        float e = expf(tot - mx);
        float sum = e + __shfl_xor(e, 1);
        sum += __shfl_xor(sum, 2);
        att4[m][sc] = e / sum;
    }
    __syncthreads();

    // ---- scale by att and store (lane = 16B unit; 1 KB contiguous per row per wave) ----
    const size_t row0 = (size_t)b * 4096 + l0;
    #pragma unroll
    for (int it = 0; it < 4; it++) {
        const int r4 = it * 4 + wave;
        const float a = att4[r4][lane >> 4];       // unit covers ch lane*8.. -> scale lane>>4
        uint4 v = *(const uint4*)&F[r4 * 520 + lane * 8];
        u32 o0 = (u32)f2bf(bf2f((u16)(v.x & 0xffffu)) * a) | ((u32)f2bf(bf2f((u16)(v.x >> 16)) * a) << 16);
        u32 o1 = (u32)f2bf(bf2f((u16)(v.y & 0xffffu)) * a) | ((u32)f2bf(bf2f((u16)(v.y >> 16)) * a) << 16);
        u32 o2 = (u32)f2bf(bf2f((u16)(v.z & 0xffffu)) * a) | ((u32)f2bf(bf2f((u16)(v.z >> 16)) * a) << 16);
        u32 o3 = (u32)f2bf(bf2f((u16)(v.w & 0xffffu)) * a) | ((u32)f2bf(bf2f((u16)(v.w >> 16)) * a) << 16);
        *(uint4*)&feats32[(row0 + r4) * 256 + lane * 4] = make_uint4(o0, o1, o2, o3);
    }
}

// ---------------- K2b: pack final_w || res_w into bf16 [512][768] ----------------
__global__ __launch_bounds__(256) void k_packw(
    const float* __restrict__ fw, const float* __restrict__ rw, u16* __restrict__ wb)
{
    const int n = blockIdx.x;
    const int k = blockIdx.y * 256 + threadIdx.x;
    float v = (k < 512) ? fw[(size_t)n * 512 + k] : rw[(size_t)n * 256 + (k - 512)];
    wb[(size_t)n * 768 + k] = f2bf(v);
}

// ---------------- K2c: pack pw1/3/5/7 into bf16 [4][128][256] ----------------
__global__ __launch_bounds__(256) void k_packpw(
    const float* __restrict__ pw1, const float* __restrict__ pw3,
    const float* __restrict__ pw5, const float* __restrict__ pw7,
    u16* __restrict__ pwb)
{
    const int s = blockIdx.y;
    const float* pw = (s == 0) ? pw1 : (s == 1) ? pw3 : (s == 2) ? pw5 : pw7;
    const int i = blockIdx.x * 256 + threadIdx.x;
    pwb[(size_t)s * 32768 + i] = f2bf(pw[i]);
}

// ---------------- K2d: pack attn_w1 into bf16 [128][512] (scratch = head of d_out) ----------
__global__ __launch_bounds__(256) void k_packw1(
    const float* __restrict__ w1, u16* __restrict__ w1b)
{
    const int i = blockIdx.x * 256 + threadIdx.x;
    w1b[i] = f2bf(w1[i]);
}

// ---------------- K3: MFMA GEMM — out[65536,512] = A[65536,768] * W[512,768]^T ----------------
__global__ __launch_bounds__(256) void k_final_mfma(
    const u16* __restrict__ feats, const float* __restrict__ x,
    const u16* __restrict__ wb, float* __restrict__ out)
{
    __shared__ __align__(16) u16 As[128 * 32];
    __shared__ __align__(16) u16 Bs[128 * 32];
    const int t = threadIdx.x;
    const int lane = t & 63;
    const int wave = t >> 6;
    const int m0 = blockIdx.x * 128;
    const int n0 = blockIdx.y * 128;

    const int srow_b = wave * 32 + (lane >> 2);
    const int sgp = lane & 3;

    f32x4 acc[4][4];
    #pragma unroll
    for (int i = 0; i < 4; i++)
        #pragma unroll
        for (int j = 0; j < 4; j++) acc[i][j] = f32x4{0.f, 0.f, 0.f, 0.f};

    const int wm = (wave & 1) * 64;
    const int wn = (wave >> 1) * 64;
    int a_off[4], b_off[4];
    #pragma unroll
    for (int i = 0; i < 4; i++) {
        int ra = wm + i * 16 + (lane & 15);
        a_off[i] = ra * 32 + (((lane >> 4) ^ ((ra >> 1) & 3)) * 8);
        int rb = wn + i * 16 + (lane & 15);
        b_off[i] = rb * 32 + (((lane >> 4) ^ ((rb >> 1) & 3)) * 8);
    }

    for (int kt = 0; kt < 24; ++kt) {
        const int k0 = kt * 32;
        #pragma unroll
        for (int j = 0; j < 2; j++) {
            int r = srow_b + j * 16;
            int g = sgp ^ ((r >> 1) & 3);
            gld_lds16(wb + (size_t)(n0 + r) * 768 + k0 + g * 8,
                      &Bs[wave * 1024 + j * 512]);
        }
        if (kt < 16) {
            #pragma unroll
            for (int j = 0; j < 2; j++) {
                int r = srow_b + j * 16;
                int g = sgp ^ ((r >> 1) & 3);
                gld_lds16(feats + (size_t)(m0 + r) * 512 + k0 + g * 8,
                          &As[wave * 1024 + j * 512]);
            }
        } else {
            const int kx0 = (kt - 16) * 32;
            const int row = t >> 1;
            #pragma unroll
            for (int h = 0; h < 2; h++) {
                int g2 = (t & 1) * 2 + h;
                const float4* xp = (const float4*)(x + (size_t)(m0 + row) * 256 + kx0 + g2 * 8);
                float4 v0 = xp[0], v1 = xp[1];
                u32 p0 = (u32)f2bf(v0.x) | ((u32)f2bf(v0.y) << 16);
                u32 p1 = (u32)f2bf(v0.z) | ((u32)f2bf(v0.w) << 16);
                u32 p2 = (u32)f2bf(v1.x) | ((u32)f2bf(v1.y) << 16);
                u32 p3 = (u32)f2bf(v1.z) | ((u32)f2bf(v1.w) << 16);
                int gp = g2 ^ ((row >> 1) & 3);
                *(uint4*)&As[row * 32 + gp * 8] = make_uint4(p0, p1, p2, p3);
            }
        }
        __syncthreads();
        bf16x8 af[4], bfr[4];
        #pragma unroll
        for (int i = 0; i < 4; i++) af[i] = *(const bf16x8*)&As[a_off[i]];
        #pragma unroll
        for (int i = 0; i < 4; i++) bfr[i] = *(const bf16x8*)&Bs[b_off[i]];
        #pragma unroll
        for (int mi = 0; mi < 4; mi++)
            #pragma unroll
            for (int ni = 0; ni < 4; ni++)
                acc[mi][ni] = __builtin_amdgcn_mfma_f32_16x16x32_bf16(
                    af[mi], bfr[ni], acc[mi][ni], 0, 0, 0);
        __syncthreads();
    }

    const int cn = n0 + wn + (lane & 15);
    const int rm = m0 + wm + (lane >> 4) * 4;
    #pragma unroll
    for (int mi = 0; mi < 4; mi++)
        #pragma unroll
        for (int ni = 0; ni < 4; ni++)
            #pragma unroll
            for (int r = 0; r < 4; r++)
                out[(size_t)(rm + mi * 16 + r) * 512 + cn + ni * 16] = acc[mi][ni][r];
}

// ---------------- K4: in-place row RMSNorm over 512 ----------------
__global__ __launch_bounds__(256) void k_norm(
    float* __restrict__ out, const float* __restrict__ nsc)
{
    __shared__ float part[2][2];
    const int t = threadIdx.x;
    const int r = t >> 7;
    const int cc = (t & 127) * 4;
    const size_t row = (size_t)blockIdx.x * 2 + r;
    float4 v = *(float4*)&out[row * 512 + cc];
    float ss = v.x * v.x + v.y * v.y + v.z * v.z + v.w * v.w;
    #pragma unroll
    for (int m = 1; m < 64; m <<= 1) ss += __shfl_xor(ss, m);
    if ((t & 63) == 0) part[r][(t >> 6) & 1] = ss;
    __syncthreads();
    float tot = part[r][0] + part[r][1];
    float rv = 1.0f / (sqrtf(tot * (1.0f / 512.0f)) + EPSF);
    const float4 s4 = *(const float4*)&nsc[cc];
    v.x *= rv * s4.x; v.y *= rv * s4.y; v.z *= rv * s4.z; v.w *= rv * s4.w;
    *(float4*)&out[row * 512 + cc] = v;
}

extern "C" void kernel_launch(void* const* d_in, const int* in_sizes, int n_in,
                              void* d_out, int out_size, void* d_ws, size_t ws_size,
                              hipStream_t stream)
{
    const float* x   = (const float*)d_in[0];
    const float* dw1 = (const float*)d_in[1];
    const float* pw1 = (const float*)d_in[2];
    const float* cn1 = (const float*)d_in[3];
    const float* dw3 = (const float*)d_in[4];
    const float* pw3 = (const float*)d_in[5];
    const float* cn3 = (const float*)d_in[6];
    const float* dw5 = (const float*)d_in[7];
    const float* pw5 = (const float*)d_in[8];
    const float* cn5 = (const float*)d_in[9];
    const float* dw7 = (const float*)d_in[10];
    const float* pw7 = (const float*)d_in[11];
    const float* cn7 = (const float*)d_in[12];
    const float* w1  = (const float*)d_in[13];
    const float* b1  = (const float*)d_in[14];
    const float* w2  = (const float*)d_in[15];
    const float* b2  = (const float*)d_in[16];
    const float* fw  = (const float*)d_in[17];
    const float* nsc = (const float*)d_in[18];
    const float* rw  = (const float*)d_in[19];

    // ws: feats bf16 [65536][512] @0 (64MB) | wb bf16 [512][768] @64MB (768KB) | pwb bf16 [4][128][256] (256KB)
    // w1b bf16 [128][512] (128KB) lives in the HEAD OF d_out (dead until k_final overwrites it)
    u16* feats = (u16*)d_ws;
    u16* wbp   = (u16*)((char*)d_ws + (size_t)67108864);
    u16* pwb   = (u16*)((char*)d_ws + (size_t)67895296);
    u16* w1b   = (u16*)d_out;
    float* out = (float*)d_out;
    if (ws_size < (size_t)68157440) return;  // loud failure if scratch too small

    k_packw<<<dim3(512, 3), 256, 0, stream>>>(fw, rw, wbp);
    k_packpw<<<dim3(128, 4), 256, 0, stream>>>(pw1, pw3, pw5, pw7, pwb);
    k_packw1<<<dim3(256), 256, 0, stream>>>(w1, w1b);
    k_feats<<<dim3(256, 16), 256, 0, stream>>>(x, dw1, dw3, dw5, dw7,
                                               cn1, cn3, cn5, cn7, pwb, w1b,
                                               b1, w2, b2, (u32*)feats);
    k_final_mfma<<<dim3(512, 4), 256, 0, stream>>>(feats, x, wbp, out);
    k_norm<<<dim3(32768), 256, 0, stream>>>(out, nsc);
}

// Round 3
// 522.751 us; speedup vs baseline: 1.3502x; 1.0024x over previous
//
#include <hip/hip_runtime.h>
#include <hip/hip_bf16.h>
#include <math.h>

typedef unsigned int u32;
typedef unsigned short u16;

typedef __bf16 bf16_t;
typedef bf16_t bf16x8 __attribute__((ext_vector_type(8)));
typedef float f32x4 __attribute__((ext_vector_type(4)));

#define EPSF 1e-8f

__device__ __forceinline__ float bf2f(u16 h) {
    union { u32 u; float f; } v; v.u = ((u32)h) << 16; return v.f;
}
__device__ __forceinline__ u16 f2bf(float f) {
    union { float ff; u32 u; } v; v.ff = f;
    u32 u = v.u;
    return (u16)((u + 0x7fffu + ((u >> 16) & 1u)) >> 16);
}
// Fast exact-gelu: erf via Abramowitz-Stegun 7.1.26 (|abs err| <= 1.5e-7), __expf + rcp.
// ~14 VALU vs ~60 for libm erff. bf16 output precision makes the 1.5e-7 invisible.
__device__ __forceinline__ float gelu_exact(float v) {
    float z = v * 0.70710678118654752440f;
    float az = fabsf(z);
    float t = __builtin_amdgcn_rcpf(__builtin_fmaf(0.3275911f, az, 1.0f));
    float p = __builtin_fmaf(1.061405429f, t, -1.453152027f);
    p = __builtin_fmaf(p, t, 1.421413741f);
    p = __builtin_fmaf(p, t, -0.284496736f);
    p = __builtin_fmaf(p, t, 0.254829592f);
    float e = __expf(-az * az);
    float erfa = 1.0f - p * t * e;
    float er = __builtin_copysignf(erfa, z);
    return 0.5f * v * (1.0f + er);
}
__device__ __forceinline__ void gld_lds16(const void* g, void* l) {
    __builtin_amdgcn_global_load_lds(
        (const __attribute__((address_space(1))) unsigned int*)g,
        (__attribute__((address_space(3))) unsigned int*)l, 16, 0, 0);
}

// ---------------- K1 (fused): conv + MFMA pointwise + RMS + GELU + attention MLP + scale ----
// Block: 16 L-positions, 256 threads (4 waves). Conv writes H[4][16][256] bf16 into exactly
// 32 KB LDS (5 blocks/CU) with 8-group XOR swizzle. Wave s GEMMs scale s (M=16,N=128,K=256),
// wave-local RMS + gelu -> F[16][520] bf16 (overlays H). part/att4 overlay dead conv scratch
// beyond F (bytes 16640..17920 of H). Attention GEMM1 M=16,N=128 from F + bf16 w1, gelu,
// w2 dot + shfl reduce, softmax, scale F, coalesced uint4 store.
template<int S>
__device__ __forceinline__ void conv_scale16(
    const float* __restrict__ dw, const float* xc, u16* __restrict__ H, int c)
{
    const int K = 2 * S + 1;
    float d[K];
    #pragma unroll
    for (int j = 0; j < K; j++) d[j] = dw[c * K + j];
    const int chunk = c & ~63;
    const int q6 = (c >> 3) & 7;
    const int jj = c & 7;
    #pragma unroll
    for (int l = 0; l < 16; l++) {
        float a = 0.f;
        #pragma unroll
        for (int j = 0; j < K; j++) a += xc[l + 3 - S + j] * d[j];
        H[(S * 16 + l) * 256 + chunk + ((q6 ^ (l & 7)) << 3) + jj] = f2bf(a);
    }
}

__global__ __launch_bounds__(256) void k_feats(
    const float* __restrict__ x,
    const float* __restrict__ dw1, const float* __restrict__ dw3,
    const float* __restrict__ dw5, const float* __restrict__ dw7,
    const float* __restrict__ cn1, const float* __restrict__ cn3,
    const float* __restrict__ cn5, const float* __restrict__ cn7,
    const u16* __restrict__ pwb, const u16* __restrict__ w1b,
    const float* __restrict__ b1, const float* __restrict__ w2,
    const float* __restrict__ b2,
    u32* __restrict__ feats32)
{
    __shared__ __align__(16) u16 H[4 * 16 * 256];   // exactly 32 KB
    // overlays into dead conv scratch (after the post-GEMM barrier): F uses u16[0..8320),
    // part at u16 8320 (1 KB), att4 at u16 8832 (256 B) -> all < 32 KB.
    float (*part)[16][4] = (float (*)[16][4])(void*)(H + 8320);
    float (*att4)[4]     = (float (*)[4])(void*)(H + 8832);
    const int t = threadIdx.x;
    const int lane = t & 63;
    const int wave = t >> 6;
    const int c15 = lane & 15;
    const int q = lane >> 4;
    const int l0 = blockIdx.x * 16;
    const int b = blockIdx.y;
    const float* xb = x + (size_t)b * 4096 * 256;

    // x column (lane = channel) in registers, fp32
    float xc[22];
    #pragma unroll
    for (int r = 0; r < 22; r++) {
        int g = l0 - 3 + r;
        xc[r] = (g >= 0 && g < 4096) ? xb[(size_t)g * 256 + t] : 0.0f;
    }
    conv_scale16<0>(dw1, xc, H, t);
    conv_scale16<1>(dw3, xc, H, t);
    conv_scale16<2>(dw5, xc, H, t);
    conv_scale16<3>(dw7, xc, H, t);
    __syncthreads();

    // ---- per-wave scale GEMM: scale s = wave, M=16 x N=128 x K=256 ----
    const int s = wave;
    const u16* wB = pwb + (size_t)s * 32768;   // [128][256] bf16
    f32x4 acc[8];
    #pragma unroll
    for (int nt = 0; nt < 8; nt++) acc[nt] = f32x4{0.f, 0.f, 0.f, 0.f};

    const int row_base = (s * 16 + c15) * 256;
    const int m7 = c15 & 7;
    #pragma unroll 2
    for (int kt = 0; kt < 8; kt++) {
        const int g7 = (((kt & 1) << 2) | q) ^ m7;
        bf16x8 af = *(const bf16x8*)&H[row_base + ((kt >> 1) << 6) + (g7 << 3)];
        #pragma unroll
        for (int nt = 0; nt < 8; nt++) {
            bf16x8 bv = *(const bf16x8*)&wB[(nt * 16 + c15) * 256 + kt * 32 + q * 8];
            acc[nt] = __builtin_amdgcn_mfma_f32_16x16x32_bf16(af, bv, acc[nt], 0, 0, 0);
        }
    }

    // ---- wave-local RMS over the 128 channels of this scale (rows m = q*4+r) ----
    float rinv_[4];
    #pragma unroll
    for (int r = 0; r < 4; r++) {
        float ss = 0.f;
        #pragma unroll
        for (int nt = 0; nt < 8; nt++) ss += acc[nt][r] * acc[nt][r];
        ss += __shfl_xor(ss, 1);
        ss += __shfl_xor(ss, 2);
        ss += __shfl_xor(ss, 4);
        ss += __shfl_xor(ss, 8);
        rinv_[r] = 1.0f / (sqrtf(ss * (1.0f / 128.0f)) + EPSF);
    }

    const float* cn = (s == 0) ? cn1 : (s == 1) ? cn3 : (s == 2) ? cn5 : cn7;
    float cnv[8];
    #pragma unroll
    for (int nt = 0; nt < 8; nt++) cnv[nt] = cn[nt * 16 + c15];

    __syncthreads();   // all GEMM reads of H complete before F overlay

    u16* F = H;        // [16][520] bf16 feats tile (row stride 520 u16, 16B-aligned rows)
    #pragma unroll
    for (int nt = 0; nt < 8; nt++)
        #pragma unroll
        for (int r = 0; r < 4; r++) {
            const int m = q * 4 + r;
            float g = gelu_exact(acc[nt][r] * rinv_[r] * cnv[nt]);
            F[m * 520 + s * 128 + nt * 16 + c15] = f2bf(g);
        }
    __syncthreads();

    // ---- attention GEMM1: a1 = F[16,512] @ w1[128,512]^T, wave covers o in [wave*32, +32) ----
    f32x4 a1[2];
    a1[0] = f32x4{0.f, 0.f, 0.f, 0.f};
    a1[1] = f32x4{0.f, 0.f, 0.f, 0.f};
    #pragma unroll 4
    for (int kt = 0; kt < 16; kt++) {
        bf16x8 av = *(const bf16x8*)&F[c15 * 520 + kt * 32 + q * 8];
        bf16x8 bv0 = *(const bf16x8*)&w1b[(size_t)(wave * 32 + c15) * 512 + kt * 32 + q * 8];
        bf16x8 bv1 = *(const bf16x8*)&w1b[(size_t)(wave * 32 + 16 + c15) * 512 + kt * 32 + q * 8];
        a1[0] = __builtin_amdgcn_mfma_f32_16x16x32_bf16(av, bv0, a1[0], 0, 0, 0);
        a1[1] = __builtin_amdgcn_mfma_f32_16x16x32_bf16(av, bv1, a1[1], 0, 0, 0);
    }
    {
        const float b1v0 = b1[wave * 32 + c15];
        const float b1v1 = b1[wave * 32 + 16 + c15];
        #pragma unroll
        for (int r = 0; r < 4; r++) {
            a1[0][r] = gelu_exact(a1[0][r] + b1v0);
            a1[1][r] = gelu_exact(a1[1][r] + b1v1);
        }
    }

    // ---- GEMM2 partials over this wave's 32 o-channels + cross-wave softmax ----
    float w2v[4][2];
    #pragma unroll
    for (int sc = 0; sc < 4; sc++) {
        w2v[sc][0] = w2[sc * 128 + wave * 32 + c15];
        w2v[sc][1] = w2[sc * 128 + wave * 32 + 16 + c15];
    }
    #pragma unroll
    for (int r = 0; r < 4; r++) {
        float g0 = a1[0][r], g1 = a1[1][r];
        float p0 = g0 * w2v[0][0] + g1 * w2v[0][1];
        float p1 = g0 * w2v[1][0] + g1 * w2v[1][1];
        float p2 = g0 * w2v[2][0] + g1 * w2v[2][1];
        float p3 = g0 * w2v[3][0] + g1 * w2v[3][1];
        #pragma unroll
        for (int msk = 1; msk < 16; msk <<= 1) {
            p0 += __shfl_xor(p0, msk);
            p1 += __shfl_xor(p1, msk);
            p2 += __shfl_xor(p2, msk);
            p3 += __shfl_xor(p3, msk);
        }
        if (c15 == 0) {
            const int m = q * 4 + r;
            part[wave][m][0] = p0; part[wave][m][1] = p1;
            part[wave][m][2] = p2; part[wave][m][3] = p3;
        }
    }
    __syncthreads();

    if (t < 64) {
        const int m = t >> 2, sc = t & 3;
        float tot = part[0][m][sc] + part[1][m][sc] + part[2][m][sc] + part[3][m][sc] + b2[sc];
        float mx = fmaxf(tot, __shfl_xor(tot, 1));
        mx = fmaxf(mx, __shfl_xor(mx, 2));
        float e = __expf(tot - mx);
        float sum = e + __shfl_xor(e, 1);
        sum += __shfl_xor(sum, 2);
        att4[m][sc] = e * __builtin_amdgcn_rcpf(sum);
    }
    __syncthreads();

    // ---- scale by att and store (lane = 16B unit; 1 KB contiguous per row per wave) ----
    const size_t row0 = (size_t)b * 4096 + l0;
    #pragma unroll
    for (int it = 0; it < 4; it++) {
        const int r4 = it * 4 + wave;
        const float a = att4[r4][lane >> 4];       // unit covers ch lane*8.. -> scale lane>>4
        uint4 v = *(const uint4*)&F[r4 * 520 + lane * 8];
        u32 o0 = (u32)f2bf(bf2f((u16)(v.x & 0xffffu)) * a) | ((u32)f2bf(bf2f((u16)(v.x >> 16)) * a) << 16);
        u32 o1 = (u32)f2bf(bf2f((u16)(v.y & 0xffffu)) * a) | ((u32)f2bf(bf2f((u16)(v.y >> 16)) * a) << 16);
        u32 o2 = (u32)f2bf(bf2f((u16)(v.z & 0xffffu)) * a) | ((u32)f2bf(bf2f((u16)(v.z >> 16)) * a) << 16);
        u32 o3 = (u32)f2bf(bf2f((u16)(v.w & 0xffffu)) * a) | ((u32)f2bf(bf2f((u16)(v.w >> 16)) * a) << 16);
        *(uint4*)&feats32[(row0 + r4) * 256 + lane * 4] = make_uint4(o0, o1, o2, o3);
    }
}

// ---------------- K2b: pack final_w || res_w into bf16 [512][768] ----------------
__global__ __launch_bounds__(256) void k_packw(
    const float* __restrict__ fw, const float* __restrict__ rw, u16* __restrict__ wb)
{
    const int n = blockIdx.x;
    const int k = blockIdx.y * 256 + threadIdx.x;
    float v = (k < 512) ? fw[(size_t)n * 512 + k] : rw[(size_t)n * 256 + (k - 512)];
    wb[(size_t)n * 768 + k] = f2bf(v);
}

// ---------------- K2c: pack pw1/3/5/7 into bf16 [4][128][256] ----------------
__global__ __launch_bounds__(256) void k_packpw(
    const float* __restrict__ pw1, const float* __restrict__ pw3,
    const float* __restrict__ pw5, const float* __restrict__ pw7,
    u16* __restrict__ pwb)
{
    const int s = blockIdx.y;
    const float* pw = (s == 0) ? pw1 : (s == 1) ? pw3 : (s == 2) ? pw5 : pw7;
    const int i = blockIdx.x * 256 + threadIdx.x;
    pwb[(size_t)s * 32768 + i] = f2bf(pw[i]);
}

// ---------------- K2d: pack attn_w1 into bf16 [128][512] (scratch = head of d_out) ----------
__global__ __launch_bounds__(256) void k_packw1(
    const float* __restrict__ w1, u16* __restrict__ w1b)
{
    const int i = blockIdx.x * 256 + threadIdx.x;
    w1b[i] = f2bf(w1[i]);
}

// ---------------- K3 (fused norm): out[65536,512] = rmsnorm( A[65536,768] @ W[512,768]^T ) ----
// Block = 64 rows x ALL 512 cols (full row => norm fuses into epilogue; k_norm deleted).
// 4 waves, each wave 64x128. B panel = entire wb (L2-resident, 768 KB); staged 32-k per step
// into 32 KB LDS (8 gld_lds16/wave). A: feats bf16 for k<512, x fp32->bf16 reg-pack for k>=512.
// Epilogue: per-row sum-sq (in-reg + shfl over 16 col-lanes + cross-wave LDS), *nsc, fp32 store.
__global__ __launch_bounds__(256, 3) void k_final_norm(
    const u16* __restrict__ feats, const float* __restrict__ x,
    const u16* __restrict__ wb, const float* __restrict__ nsc,
    float* __restrict__ out)
{
    __shared__ __align__(16) u16 As[64 * 32];     // 4 KB
    __shared__ __align__(16) u16 Bs[512 * 32];    // 32 KB; epilogue overlays part[4][64] f32
    float* part = (float*)Bs;
    const int t = threadIdx.x;
    const int lane = t & 63;
    const int wave = t >> 6;
    const int c15 = lane & 15;
    const int q = lane >> 4;
    const int m0 = blockIdx.x * 64;
    const int wn = wave * 128;

    f32x4 acc[4][8];
    #pragma unroll
    for (int i = 0; i < 4; i++)
        #pragma unroll
        for (int j = 0; j < 8; j++) acc[i][j] = f32x4{0.f, 0.f, 0.f, 0.f};

    // fragment read offsets (constant across kt): row = tile*16 + c15 -> swizzle g = q ^ ((c15>>1)&3)
    const int gr = (q ^ ((c15 >> 1) & 3)) * 8;
    int a_off[4], b_off[8];
    #pragma unroll
    for (int i = 0; i < 4; i++) a_off[i] = (i * 16 + c15) * 32 + gr;
    #pragma unroll
    for (int i = 0; i < 8; i++) b_off[i] = (wn + i * 16 + c15) * 32 + gr;

    // staging lane roles
    const int srow = lane >> 2;          // 0..15 within a 16-row group
    const int sg = lane & 3;             // 16B unit within row

    for (int kt = 0; kt < 24; ++kt) {
        const int k0 = kt * 32;
        // ---- B: 512 rows x 32 k, 8 issues per wave (16 rows each) ----
        #pragma unroll
        for (int i = 0; i < 8; i++) {
            const int rb = (wave * 8 + i) * 16 + srow;
            const int g = sg ^ ((rb >> 1) & 3);
            gld_lds16(wb + (size_t)rb * 768 + k0 + g * 8, &Bs[(wave * 8 + i) * 512]);
        }
        // ---- A: 64 rows x 32 k ----
        if (kt < 16) {
            const int ra = wave * 16 + srow;
            const int g = sg ^ ((ra >> 1) & 3);
            gld_lds16(feats + (size_t)(m0 + ra) * 512 + k0 + g * 8, &As[wave * 512]);
        } else {
            const int kx0 = (kt - 16) * 32;
            const int row = t >> 2;
            const int g2 = t & 3;
            const float4* xp = (const float4*)(x + (size_t)(m0 + row) * 256 + kx0 + g2 * 8);
            float4 v0 = xp[0], v1 = xp[1];
            u32 p0 = (u32)f2bf(v0.x) | ((u32)f2bf(v0.y) << 16);
            u32 p1 = (u32)f2bf(v0.z) | ((u32)f2bf(v0.w) << 16);
            u32 p2 = (u32)f2bf(v1.x) | ((u32)f2bf(v1.y) << 16);
            u32 p3 = (u32)f2bf(v1.z) | ((u32)f2bf(v1.w) << 16);
            const int gp = g2 ^ ((row >> 1) & 3);
            *(uint4*)&As[row * 32 + gp * 8] = make_uint4(p0, p1, p2, p3);
        }
        __syncthreads();
        bf16x8 af[4];
        #pragma unroll
        for (int i = 0; i < 4; i++) af[i] = *(const bf16x8*)&As[a_off[i]];
        #pragma unroll
        for (int ni = 0; ni < 8; ni++) {
            bf16x8 bv = *(const bf16x8*)&Bs[b_off[ni]];
            #pragma unroll
            for (int mi = 0; mi < 4; mi++)
                acc[mi][ni] = __builtin_amdgcn_mfma_f32_16x16x32_bf16(
                    af[mi], bv, acc[mi][ni], 0, 0, 0);
        }
        __syncthreads();
    }

    // ---- epilogue: row sum-of-squares -> rinv, * nsc, fp32 store ----
    #pragma unroll
    for (int mi = 0; mi < 4; mi++)
        #pragma unroll
        for (int r = 0; r < 4; r++) {
            float ss = 0.f;
            #pragma unroll
            for (int ni = 0; ni < 8; ni++) ss += acc[mi][ni][r] * acc[mi][ni][r];
            ss += __shfl_xor(ss, 1);
            ss += __shfl_xor(ss, 2);
            ss += __shfl_xor(ss, 4);
            ss += __shfl_xor(ss, 8);
            if (c15 == 0) part[wave * 64 + mi * 16 + q * 4 + r] = ss;
        }
    __syncthreads();

    float nscv[8];
    #pragma unroll
    for (int ni = 0; ni < 8; ni++) nscv[ni] = nsc[wn + ni * 16 + c15];

    #pragma unroll
    for (int mi = 0; mi < 4; mi++) {
        #pragma unroll
        for (int r = 0; r < 4; r++) {
            const int row = mi * 16 + q * 4 + r;
            float tot = part[0 * 64 + row] + part[1 * 64 + row]
                      + part[2 * 64 + row] + part[3 * 64 + row];
            float rv = 1.0f / (sqrtf(tot * (1.0f / 512.0f)) + EPSF);
            float* orow = out + (size_t)(m0 + row) * 512 + wn + c15;
            #pragma unroll
            for (int ni = 0; ni < 8; ni++)
                orow[ni * 16] = acc[mi][ni][r] * rv * nscv[ni];
        }
    }
}

extern "C" void kernel_launch(void* const* d_in, const int* in_sizes, int n_in,
                              void* d_out, int out_size, void* d_ws, size_t ws_size,
                              hipStream_t stream)
{
    const float* x   = (const float*)d_in[0];
    const float* dw1 = (const float*)d_in[1];
    const float* pw1 = (const float*)d_in[2];
    const float* cn1 = (const float*)d_in[3];
    const float* dw3 = (const float*)d_in[4];
    const float* pw3 = (const float*)d_in[5];
    const float* cn3 = (const float*)d_in[6];
    const float* dw5 = (const float*)d_in[7];
    const float* pw5 = (const float*)d_in[8];
    const float* cn5 = (const float*)d_in[9];
    const float* dw7 = (const float*)d_in[10];
    const float* pw7 = (const float*)d_in[11];
    const float* cn7 = (const float*)d_in[12];
    const float* w1  = (const float*)d_in[13];
    const float* b1  = (const float*)d_in[14];
    const float* w2  = (const float*)d_in[15];
    const float* b2  = (const float*)d_in[16];
    const float* fw  = (const float*)d_in[17];
    const float* nsc = (const float*)d_in[18];
    const float* rw  = (const float*)d_in[19];

    // ws: feats bf16 [65536][512] @0 (64MB) | wb bf16 [512][768] @64MB (768KB) | pwb bf16 [4][128][256] (256KB)
    // w1b bf16 [128][512] (128KB) lives in the HEAD OF d_out (dead until k_final_norm overwrites it)
    u16* feats = (u16*)d_ws;
    u16* wbp   = (u16*)((char*)d_ws + (size_t)67108864);
    u16* pwb   = (u16*)((char*)d_ws + (size_t)67895296);
    u16* w1b   = (u16*)d_out;
    float* out = (float*)d_out;
    if (ws_size < (size_t)68157440) return;  // loud failure if scratch too small

    k_packw<<<dim3(512, 3), 256, 0, stream>>>(fw, rw, wbp);
    k_packpw<<<dim3(128, 4), 256, 0, stream>>>(pw1, pw3, pw5, pw7, pwb);
    k_packw1<<<dim3(256), 256, 0, stream>>>(w1, w1b);
    k_feats<<<dim3(256, 16), 256, 0, stream>>>(x, dw1, dw3, dw5, dw7,
                                               cn1, cn3, cn5, cn7, pwb, w1b,
                                               b1, w2, b2, (u32*)feats);
    k_final_norm<<<dim3(1024), 256, 0, stream>>>(feats, x, wbp, nsc, out);
}

// Round 4
// 432.852 us; speedup vs baseline: 1.6306x; 1.2077x over previous
//
#include <hip/hip_runtime.h>
#include <hip/hip_bf16.h>
#include <math.h>

typedef unsigned int u32;
typedef unsigned short u16;

typedef __bf16 bf16_t;
typedef bf16_t bf16x8 __attribute__((ext_vector_type(8)));
typedef float f32x4 __attribute__((ext_vector_type(4)));

#define EPSF 1e-8f

__device__ __forceinline__ float bf2f(u16 h) {
    union { u32 u; float f; } v; v.u = ((u32)h) << 16; return v.f;
}
__device__ __forceinline__ u16 f2bf(float f) {
    union { float ff; u32 u; } v; v.ff = f;
    u32 u = v.u;
    return (u16)((u + 0x7fffu + ((u >> 16) & 1u)) >> 16);
}
// Fast exact-gelu: erf via Abramowitz-Stegun 7.1.26 (|abs err| <= 1.5e-7), __expf + rcp.
__device__ __forceinline__ float gelu_exact(float v) {
    float z = v * 0.70710678118654752440f;
    float az = fabsf(z);
    float t = __builtin_amdgcn_rcpf(__builtin_fmaf(0.3275911f, az, 1.0f));
    float p = __builtin_fmaf(1.061405429f, t, -1.453152027f);
    p = __builtin_fmaf(p, t, 1.421413741f);
    p = __builtin_fmaf(p, t, -0.284496736f);
    p = __builtin_fmaf(p, t, 0.254829592f);
    float e = __expf(-az * az);
    float erfa = 1.0f - p * t * e;
    float er = __builtin_copysignf(erfa, z);
    return 0.5f * v * (1.0f + er);
}
__device__ __forceinline__ void gld_lds16(const void* g, void* l) {
    __builtin_amdgcn_global_load_lds(
        (const __attribute__((address_space(1))) unsigned int*)g,
        (__attribute__((address_space(3))) unsigned int*)l, 16, 0, 0);
}

// ---------------- K1 (fused): conv + MFMA pointwise + RMS + GELU + attention MLP + scale ----
// Weight panels (pwb, w1b) are FRAGMENT-ORDERED: chunk (kt*8+nt) of 512 bf16 = one wave's
// B-fragment, loaded as lane*8 -> 1 KB contiguous per wave instruction (was a 16-line gather).
template<int S>
__device__ __forceinline__ void conv_scale16(
    const float* __restrict__ dw, const float* xc, u16* __restrict__ H, int c)
{
    const int K = 2 * S + 1;
    float d[K];
    #pragma unroll
    for (int j = 0; j < K; j++) d[j] = dw[c * K + j];
    const int chunk = c & ~63;
    const int q6 = (c >> 3) & 7;
    const int jj = c & 7;
    #pragma unroll
    for (int l = 0; l < 16; l++) {
        float a = 0.f;
        #pragma unroll
        for (int j = 0; j < K; j++) a += xc[l + 3 - S + j] * d[j];
        H[(S * 16 + l) * 256 + chunk + ((q6 ^ (l & 7)) << 3) + jj] = f2bf(a);
    }
}

__global__ __launch_bounds__(256) void k_feats(
    const float* __restrict__ x,
    const float* __restrict__ dw1, const float* __restrict__ dw3,
    const float* __restrict__ dw5, const float* __restrict__ dw7,
    const float* __restrict__ cn1, const float* __restrict__ cn3,
    const float* __restrict__ cn5, const float* __restrict__ cn7,
    const u16* __restrict__ pwb, const u16* __restrict__ w1b,
    const float* __restrict__ b1, const float* __restrict__ w2,
    const float* __restrict__ b2,
    u32* __restrict__ feats32)
{
    __shared__ __align__(16) u16 H[4 * 16 * 256];   // exactly 32 KB
    float (*part)[16][4] = (float (*)[16][4])(void*)(H + 8320);
    float (*att4)[4]     = (float (*)[4])(void*)(H + 8832);
    const int t = threadIdx.x;
    const int lane = t & 63;
    const int wave = t >> 6;
    const int c15 = lane & 15;
    const int q = lane >> 4;
    const int l0 = blockIdx.x * 16;
    const int b = blockIdx.y;
    const float* xb = x + (size_t)b * 4096 * 256;

    // x column (lane = channel) in registers, fp32
    float xc[22];
    #pragma unroll
    for (int r = 0; r < 22; r++) {
        int g = l0 - 3 + r;
        xc[r] = (g >= 0 && g < 4096) ? xb[(size_t)g * 256 + t] : 0.0f;
    }
    conv_scale16<0>(dw1, xc, H, t);
    conv_scale16<1>(dw3, xc, H, t);
    conv_scale16<2>(dw5, xc, H, t);
    conv_scale16<3>(dw7, xc, H, t);
    __syncthreads();

    // ---- per-wave scale GEMM: scale s = wave, M=16 x N=128 x K=256 (B fragment-ordered) ----
    const int s = wave;
    const u16* wBf = pwb + (size_t)s * 32768;   // [8 kt][8 nt][512] bf16 fragments
    f32x4 acc[8];
    #pragma unroll
    for (int nt = 0; nt < 8; nt++) acc[nt] = f32x4{0.f, 0.f, 0.f, 0.f};

    const int row_base = (s * 16 + c15) * 256;
    const int m7 = c15 & 7;
    #pragma unroll 2
    for (int kt = 0; kt < 8; kt++) {
        const int g7 = (((kt & 1) << 2) | q) ^ m7;
        bf16x8 af = *(const bf16x8*)&H[row_base + ((kt >> 1) << 6) + (g7 << 3)];
        #pragma unroll
        for (int nt = 0; nt < 8; nt++) {
            bf16x8 bv = *(const bf16x8*)&wBf[(kt * 8 + nt) * 512 + lane * 8];
            acc[nt] = __builtin_amdgcn_mfma_f32_16x16x32_bf16(af, bv, acc[nt], 0, 0, 0);
        }
    }

    // ---- wave-local RMS over the 128 channels of this scale (rows m = q*4+r) ----
    float rinv_[4];
    #pragma unroll
    for (int r = 0; r < 4; r++) {
        float ss = 0.f;
        #pragma unroll
        for (int nt = 0; nt < 8; nt++) ss += acc[nt][r] * acc[nt][r];
        ss += __shfl_xor(ss, 1);
        ss += __shfl_xor(ss, 2);
        ss += __shfl_xor(ss, 4);
        ss += __shfl_xor(ss, 8);
        rinv_[r] = 1.0f / (sqrtf(ss * (1.0f / 128.0f)) + EPSF);
    }

    const float* cn = (s == 0) ? cn1 : (s == 1) ? cn3 : (s == 2) ? cn5 : cn7;
    float cnv[8];
    #pragma unroll
    for (int nt = 0; nt < 8; nt++) cnv[nt] = cn[nt * 16 + c15];

    __syncthreads();   // all GEMM reads of H complete before F overlay

    u16* F = H;        // [16][520] bf16 feats tile
    #pragma unroll
    for (int nt = 0; nt < 8; nt++)
        #pragma unroll
        for (int r = 0; r < 4; r++) {
            const int m = q * 4 + r;
            float g = gelu_exact(acc[nt][r] * rinv_[r] * cnv[nt]);
            F[m * 520 + s * 128 + nt * 16 + c15] = f2bf(g);
        }
    __syncthreads();

    // ---- attention GEMM1: a1 = F[16,512] @ w1[128,512]^T (w1 fragment-ordered) ----
    f32x4 a1[2];
    a1[0] = f32x4{0.f, 0.f, 0.f, 0.f};
    a1[1] = f32x4{0.f, 0.f, 0.f, 0.f};
    #pragma unroll 4
    for (int kt = 0; kt < 16; kt++) {
        bf16x8 av = *(const bf16x8*)&F[c15 * 520 + kt * 32 + q * 8];
        bf16x8 bv0 = *(const bf16x8*)&w1b[(kt * 8 + wave * 2) * 512 + lane * 8];
        bf16x8 bv1 = *(const bf16x8*)&w1b[(kt * 8 + wave * 2 + 1) * 512 + lane * 8];
        a1[0] = __builtin_amdgcn_mfma_f32_16x16x32_bf16(av, bv0, a1[0], 0, 0, 0);
        a1[1] = __builtin_amdgcn_mfma_f32_16x16x32_bf16(av, bv1, a1[1], 0, 0, 0);
    }
    {
        const float b1v0 = b1[wave * 32 + c15];
        const float b1v1 = b1[wave * 32 + 16 + c15];
        #pragma unroll
        for (int r = 0; r < 4; r++) {
            a1[0][r] = gelu_exact(a1[0][r] + b1v0);
            a1[1][r] = gelu_exact(a1[1][r] + b1v1);
        }
    }

    // ---- GEMM2 partials over this wave's 32 o-channels + cross-wave softmax ----
    float w2v[4][2];
    #pragma unroll
    for (int sc = 0; sc < 4; sc++) {
        w2v[sc][0] = w2[sc * 128 + wave * 32 + c15];
        w2v[sc][1] = w2[sc * 128 + wave * 32 + 16 + c15];
    }
    #pragma unroll
    for (int r = 0; r < 4; r++) {
        float g0 = a1[0][r], g1 = a1[1][r];
        float p0 = g0 * w2v[0][0] + g1 * w2v[0][1];
        float p1 = g0 * w2v[1][0] + g1 * w2v[1][1];
        float p2 = g0 * w2v[2][0] + g1 * w2v[2][1];
        float p3 = g0 * w2v[3][0] + g1 * w2v[3][1];
        #pragma unroll
        for (int msk = 1; msk < 16; msk <<= 1) {
            p0 += __shfl_xor(p0, msk);
            p1 += __shfl_xor(p1, msk);
            p2 += __shfl_xor(p2, msk);
            p3 += __shfl_xor(p3, msk);
        }
        if (c15 == 0) {
            const int m = q * 4 + r;
            part[wave][m][0] = p0; part[wave][m][1] = p1;
            part[wave][m][2] = p2; part[wave][m][3] = p3;
        }
    }
    __syncthreads();

    if (t < 64) {
        const int m = t >> 2, sc = t & 3;
        float tot = part[0][m][sc] + part[1][m][sc] + part[2][m][sc] + part[3][m][sc] + b2[sc];
        float mx = fmaxf(tot, __shfl_xor(tot, 1));
        mx = fmaxf(mx, __shfl_xor(mx, 2));
        float e = __expf(tot - mx);
        float sum = e + __shfl_xor(e, 1);
        sum += __shfl_xor(sum, 2);
        att4[m][sc] = e * __builtin_amdgcn_rcpf(sum);
    }
    __syncthreads();

    // ---- scale by att and store (lane = 16B unit; 1 KB contiguous per row per wave) ----
    const size_t row0 = (size_t)b * 4096 + l0;
    #pragma unroll
    for (int it = 0; it < 4; it++) {
        const int r4 = it * 4 + wave;
        const float a = att4[r4][lane >> 4];
        uint4 v = *(const uint4*)&F[r4 * 520 + lane * 8];
        u32 o0 = (u32)f2bf(bf2f((u16)(v.x & 0xffffu)) * a) | ((u32)f2bf(bf2f((u16)(v.x >> 16)) * a) << 16);
        u32 o1 = (u32)f2bf(bf2f((u16)(v.y & 0xffffu)) * a) | ((u32)f2bf(bf2f((u16)(v.y >> 16)) * a) << 16);
        u32 o2 = (u32)f2bf(bf2f((u16)(v.z & 0xffffu)) * a) | ((u32)f2bf(bf2f((u16)(v.z >> 16)) * a) << 16);
        u32 o3 = (u32)f2bf(bf2f((u16)(v.w & 0xffffu)) * a) | ((u32)f2bf(bf2f((u16)(v.w >> 16)) * a) << 16);
        *(uint4*)&feats32[(row0 + r4) * 256 + lane * 4] = make_uint4(o0, o1, o2, o3);
    }
}

// ---------------- K2b: pack final_w || res_w into FRAGMENT-ORDERED bf16 [24 kt][32 nchunk][512] ----
// chunk (kt*32 + nw*8 + ni) holds B-fragment for cols n = nw*128+ni*16+c15, k = kt*32+q*8+j,
// element at q*128 + c15*8 + j (= lane*8 + j). One wave load = 1 KB contiguous.
__global__ __launch_bounds__(256) void k_packw(
    const float* __restrict__ fw, const float* __restrict__ rw, u16* __restrict__ wbf)
{
    const int n = blockIdx.x;                       // 0..511
    const int k = blockIdx.y * 256 + threadIdx.x;   // 0..767
    float v = (k < 512) ? fw[(size_t)n * 512 + k] : rw[(size_t)n * 256 + (k - 512)];
    const int kt = k >> 5, q = (k >> 3) & 3, j = k & 7;
    const int nw = n >> 7, ni = (n >> 4) & 7, c15 = n & 15;
    wbf[(size_t)(kt * 32 + nw * 8 + ni) * 512 + q * 128 + c15 * 8 + j] = f2bf(v);
}

// ---------------- K2c: pack pw1/3/5/7 into fragment-ordered bf16 [4][8 kt][8 nt][512] -------
__global__ __launch_bounds__(256) void k_packpw(
    const float* __restrict__ pw1, const float* __restrict__ pw3,
    const float* __restrict__ pw5, const float* __restrict__ pw7,
    u16* __restrict__ pwb)
{
    const int s = blockIdx.y;
    const float* pw = (s == 0) ? pw1 : (s == 1) ? pw3 : (s == 2) ? pw5 : pw7;
    const int i = blockIdx.x * 256 + threadIdx.x;   // o*256 + c
    const int o = i >> 8, c = i & 255;
    const int dst = ((c >> 5) * 8 + (o >> 4)) * 512 + ((c >> 3) & 3) * 128 + (o & 15) * 8 + (c & 7);
    pwb[(size_t)s * 32768 + dst] = f2bf(pw[i]);
}

// ---------------- K2d: pack attn_w1 into fragment-ordered bf16 [16 kt][8 nt][512] -----------
__global__ __launch_bounds__(256) void k_packw1(
    const float* __restrict__ w1, u16* __restrict__ w1b)
{
    const int i = blockIdx.x * 256 + threadIdx.x;   // o*512 + c
    const int o = i >> 9, c = i & 511;
    const int dst = ((c >> 5) * 8 + (o >> 4)) * 512 + ((c >> 3) & 3) * 128 + (o & 15) * 8 + (c & 7);
    w1b[dst] = f2bf(w1[i]);
}

// ---------------- K3 (barrier-free K-loop): out = rmsnorm( A[65536,768] @ W[512,768]^T ) ----
// 512 threads (8 waves = 2m x 4n), 64 rows/block. A staged ONCE: feats 64KB (gld_lds, XOR-unit
// swizzle via pre-swizzled source) + x packed to bf16 32KB (ds_write, same swizzle). One
// barrier total before the K-loop; B streams from L2 in fragment-ordered 1KB wave loads
// straight into MFMA -- no staging, no vmcnt(0) drains, no per-step barriers.
// Epilogue: cross-wave row sum-sq via LDS part, *nsc, fp32 store.
__global__ __launch_bounds__(512, 2) void k_final_norm(
    const u16* __restrict__ feats, const float* __restrict__ x,
    const u16* __restrict__ wbf, const float* __restrict__ nsc,
    float* __restrict__ out)
{
    __shared__ __align__(16) u16 Fa[64 * 512];   // 64 KB, unit-swizzled (u ^= row&15)
    __shared__ __align__(16) u16 Xa[64 * 256];   // 32 KB, unit-swizzled
    __shared__ float part[2][32][4];
    const int t = threadIdx.x;
    const int lane = t & 63;
    const int wave = t >> 6;          // 0..7
    const int c15 = lane & 15;
    const int q = lane >> 4;
    const int mw = wave >> 2;         // 0..1  (32-row half)
    const int nw = wave & 3;          // 0..3  (128-col quarter)
    const int m0 = blockIdx.x * 64;

    // ---- stage feats[64][512] -> Fa (linear dest, inverse-swizzled source) ----
    #pragma unroll
    for (int i = 0; i < 8; i++) {
        const int r = i * 8 + wave;
        gld_lds16(feats + (size_t)(m0 + r) * 512 + (size_t)((lane ^ (r & 15)) * 8),
                  &Fa[r * 512]);
    }
    // ---- stage x[64][256] -> bf16 Xa (swizzled ds_write) ----
    {
        const int r = t >> 3, sub = t & 7;
        const float4* xp = (const float4*)(x + (size_t)(m0 + r) * 256 + sub * 32);
        #pragma unroll
        for (int uu = 0; uu < 4; uu++) {
            float4 v0 = xp[2 * uu], v1 = xp[2 * uu + 1];
            u32 p0 = (u32)f2bf(v0.x) | ((u32)f2bf(v0.y) << 16);
            u32 p1 = (u32)f2bf(v0.z) | ((u32)f2bf(v0.w) << 16);
            u32 p2 = (u32)f2bf(v1.x) | ((u32)f2bf(v1.y) << 16);
            u32 p3 = (u32)f2bf(v1.z) | ((u32)f2bf(v1.w) << 16);
            const int u = (sub * 4 + uu) ^ (r & 15);
            *(uint4*)&Xa[r * 256 + u * 8] = make_uint4(p0, p1, p2, p3);
        }
    }
    __syncthreads();   // the ONLY pre-epilogue barrier

    f32x4 acc[2][8];
    #pragma unroll
    for (int i = 0; i < 2; i++)
        #pragma unroll
        for (int j = 0; j < 8; j++) acc[i][j] = f32x4{0.f, 0.f, 0.f, 0.f};

    const int ra0 = mw * 32 + c15;
    const int ra1 = mw * 32 + 16 + c15;

    // ---- K-loop part 1: k in [0,512) from Fa ----
    #pragma unroll 2
    for (int kt = 0; kt < 16; ++kt) {
        bf16x8 af0 = *(const bf16x8*)&Fa[ra0 * 512 + (((kt * 4 + q) ^ (ra0 & 15)) * 8)];
        bf16x8 af1 = *(const bf16x8*)&Fa[ra1 * 512 + (((kt * 4 + q) ^ (ra1 & 15)) * 8)];
        #pragma unroll
        for (int ni = 0; ni < 8; ni++) {
            bf16x8 bv = *(const bf16x8*)&wbf[(size_t)(kt * 32 + nw * 8 + ni) * 512 + lane * 8];
            acc[0][ni] = __builtin_amdgcn_mfma_f32_16x16x32_bf16(af0, bv, acc[0][ni], 0, 0, 0);
            acc[1][ni] = __builtin_amdgcn_mfma_f32_16x16x32_bf16(af1, bv, acc[1][ni], 0, 0, 0);
        }
    }
    // ---- K-loop part 2: k in [512,768) from Xa ----
    #pragma unroll 2
    for (int kt = 16; kt < 24; ++kt) {
        const int v2 = (kt - 16) * 4 + q;
        bf16x8 af0 = *(const bf16x8*)&Xa[ra0 * 256 + ((v2 ^ (ra0 & 15)) * 8)];
        bf16x8 af1 = *(const bf16x8*)&Xa[ra1 * 256 + ((v2 ^ (ra1 & 15)) * 8)];
        #pragma unroll
        for (int ni = 0; ni < 8; ni++) {
            bf16x8 bv = *(const bf16x8*)&wbf[(size_t)(kt * 32 + nw * 8 + ni) * 512 + lane * 8];
            acc[0][ni] = __builtin_amdgcn_mfma_f32_16x16x32_bf16(af0, bv, acc[0][ni], 0, 0, 0);
            acc[1][ni] = __builtin_amdgcn_mfma_f32_16x16x32_bf16(af1, bv, acc[1][ni], 0, 0, 0);
        }
    }

    // ---- epilogue: row sum-of-squares across 4 n-waves -> rinv, *nsc, fp32 store ----
    #pragma unroll
    for (int mt = 0; mt < 2; mt++)
        #pragma unroll
        for (int r = 0; r < 4; r++) {
            float ss = 0.f;
            #pragma unroll
            for (int ni = 0; ni < 8; ni++) ss += acc[mt][ni][r] * acc[mt][ni][r];
            ss += __shfl_xor(ss, 1);
            ss += __shfl_xor(ss, 2);
            ss += __shfl_xor(ss, 4);
            ss += __shfl_xor(ss, 8);
            if (c15 == 0) part[mw][mt * 16 + q * 4 + r][nw] = ss;
        }
    __syncthreads();

    float nscv[8];
    #pragma unroll
    for (int ni = 0; ni < 8; ni++) nscv[ni] = nsc[nw * 128 + ni * 16 + c15];

    #pragma unroll
    for (int mt = 0; mt < 2; mt++) {
        #pragma unroll
        for (int r = 0; r < 4; r++) {
            const int row = mt * 16 + q * 4 + r;
            float tot = part[mw][row][0] + part[mw][row][1]
                      + part[mw][row][2] + part[mw][row][3];
            float rv = 1.0f / (sqrtf(tot * (1.0f / 512.0f)) + EPSF);
            float* orow = out + (size_t)(m0 + mw * 32 + row) * 512 + nw * 128 + c15;
            #pragma unroll
            for (int ni = 0; ni < 8; ni++)
                orow[ni * 16] = acc[mt][ni][r] * rv * nscv[ni];
        }
    }
}

extern "C" void kernel_launch(void* const* d_in, const int* in_sizes, int n_in,
                              void* d_out, int out_size, void* d_ws, size_t ws_size,
                              hipStream_t stream)
{
    const float* x   = (const float*)d_in[0];
    const float* dw1 = (const float*)d_in[1];
    const float* pw1 = (const float*)d_in[2];
    const float* cn1 = (const float*)d_in[3];
    const float* dw3 = (const float*)d_in[4];
    const float* pw3 = (const float*)d_in[5];
    const float* cn3 = (const float*)d_in[6];
    const float* dw5 = (const float*)d_in[7];
    const float* pw5 = (const float*)d_in[8];
    const float* cn5 = (const float*)d_in[9];
    const float* dw7 = (const float*)d_in[10];
    const float* pw7 = (const float*)d_in[11];
    const float* cn7 = (const float*)d_in[12];
    const float* w1  = (const float*)d_in[13];
    const float* b1  = (const float*)d_in[14];
    const float* w2  = (const float*)d_in[15];
    const float* b2  = (const float*)d_in[16];
    const float* fw  = (const float*)d_in[17];
    const float* nsc = (const float*)d_in[18];
    const float* rw  = (const float*)d_in[19];

    // ws: feats bf16 [65536][512] @0 (64MB) | wbf bf16 frag-ordered (768KB) | pwb frag-ordered (256KB)
    // w1b bf16 frag-ordered (128KB) lives in the HEAD OF d_out (dead until k_final_norm overwrites it)
    u16* feats = (u16*)d_ws;
    u16* wbf   = (u16*)((char*)d_ws + (size_t)67108864);
    u16* pwb   = (u16*)((char*)d_ws + (size_t)67895296);
    u16* w1b   = (u16*)d_out;
    float* out = (float*)d_out;
    if (ws_size < (size_t)68157440) return;  // loud failure if scratch too small

    k_packw<<<dim3(512, 3), 256, 0, stream>>>(fw, rw, wbf);
    k_packpw<<<dim3(128, 4), 256, 0, stream>>>(pw1, pw3, pw5, pw7, pwb);
    k_packw1<<<dim3(256), 256, 0, stream>>>(w1, w1b);
    k_feats<<<dim3(256, 16), 256, 0, stream>>>(x, dw1, dw3, dw5, dw7,
                                               cn1, cn3, cn5, cn7, pwb, w1b,
                                               b1, w2, b2, (u32*)feats);
    k_final_norm<<<dim3(1024), 512, 0, stream>>>(feats, x, wbf, nsc, out);
}

// Round 5
// 410.431 us; speedup vs baseline: 1.7197x; 1.0546x over previous
//
#include <hip/hip_runtime.h>
#include <hip/hip_bf16.h>
#include <math.h>

typedef unsigned int u32;
typedef unsigned short u16;

typedef __bf16 bf16_t;
typedef bf16_t bf16x8 __attribute__((ext_vector_type(8)));
typedef float f32x4 __attribute__((ext_vector_type(4)));

#define EPSF 1e-8f

__device__ __forceinline__ float bf2f(u16 h) {
    union { u32 u; float f; } v; v.u = ((u32)h) << 16; return v.f;
}
__device__ __forceinline__ u16 f2bf(float f) {
    union { float ff; u32 u; } v; v.ff = f;
    u32 u = v.u;
    return (u16)((u + 0x7fffu + ((u >> 16) & 1u)) >> 16);
}
// Fast exact-gelu: erf via Abramowitz-Stegun 7.1.26 (|abs err| <= 1.5e-7), __expf + rcp.
__device__ __forceinline__ float gelu_exact(float v) {
    float z = v * 0.70710678118654752440f;
    float az = fabsf(z);
    float t = __builtin_amdgcn_rcpf(__builtin_fmaf(0.3275911f, az, 1.0f));
    float p = __builtin_fmaf(1.061405429f, t, -1.453152027f);
    p = __builtin_fmaf(p, t, 1.421413741f);
    p = __builtin_fmaf(p, t, -0.284496736f);
    p = __builtin_fmaf(p, t, 0.254829592f);
    float e = __expf(-az * az);
    float erfa = 1.0f - p * t * e;
    float er = __builtin_copysignf(erfa, z);
    return 0.5f * v * (1.0f + er);
}
__device__ __forceinline__ void gld_lds16(const void* g, void* l) {
    __builtin_amdgcn_global_load_lds(
        (const __attribute__((address_space(1))) unsigned int*)g,
        (__attribute__((address_space(3))) unsigned int*)l, 16, 0, 0);
}

// ---------------- K1 (fused): conv + MFMA pointwise + RMS + GELU + attention MLP + scale ----
// Weight panels (pwb, w1b) are FRAGMENT-ORDERED: chunk (kt*8+nt) of 512 bf16 = one wave's
// B-fragment, loaded as lane*8 -> 1 KB contiguous per wave instruction.
template<int S>
__device__ __forceinline__ void conv_scale16(
    const float* __restrict__ dw, const float* xc, u16* __restrict__ H, int c)
{
    const int K = 2 * S + 1;
    float d[K];
    #pragma unroll
    for (int j = 0; j < K; j++) d[j] = dw[c * K + j];
    const int chunk = c & ~63;
    const int q6 = (c >> 3) & 7;
    const int jj = c & 7;
    #pragma unroll
    for (int l = 0; l < 16; l++) {
        float a = 0.f;
        #pragma unroll
        for (int j = 0; j < K; j++) a += xc[l + 3 - S + j] * d[j];
        H[(S * 16 + l) * 256 + chunk + ((q6 ^ (l & 7)) << 3) + jj] = f2bf(a);
    }
}

__global__ __launch_bounds__(256) void k_feats(
    const float* __restrict__ x,
    const float* __restrict__ dw1, const float* __restrict__ dw3,
    const float* __restrict__ dw5, const float* __restrict__ dw7,
    const float* __restrict__ cn1, const float* __restrict__ cn3,
    const float* __restrict__ cn5, const float* __restrict__ cn7,
    const u16* __restrict__ pwb, const u16* __restrict__ w1b,
    const float* __restrict__ b1, const float* __restrict__ w2,
    const float* __restrict__ b2,
    u32* __restrict__ feats32)
{
    __shared__ __align__(16) u16 H[4 * 16 * 256];   // exactly 32 KB
    float (*part)[16][4] = (float (*)[16][4])(void*)(H + 8320);
    float (*att4)[4]     = (float (*)[4])(void*)(H + 8832);
    const int t = threadIdx.x;
    const int lane = t & 63;
    const int wave = t >> 6;
    const int c15 = lane & 15;
    const int q = lane >> 4;
    const int l0 = blockIdx.x * 16;
    const int b = blockIdx.y;
    const float* xb = x + (size_t)b * 4096 * 256;

    // x column (lane = channel) in registers, fp32
    float xc[22];
    #pragma unroll
    for (int r = 0; r < 22; r++) {
        int g = l0 - 3 + r;
        xc[r] = (g >= 0 && g < 4096) ? xb[(size_t)g * 256 + t] : 0.0f;
    }
    conv_scale16<0>(dw1, xc, H, t);
    conv_scale16<1>(dw3, xc, H, t);
    conv_scale16<2>(dw5, xc, H, t);
    conv_scale16<3>(dw7, xc, H, t);
    __syncthreads();

    // ---- per-wave scale GEMM: scale s = wave, M=16 x N=128 x K=256 (B fragment-ordered) ----
    const int s = wave;
    const u16* wBf = pwb + (size_t)s * 32768;   // [8 kt][8 nt][512] bf16 fragments
    f32x4 acc[8];
    #pragma unroll
    for (int nt = 0; nt < 8; nt++) acc[nt] = f32x4{0.f, 0.f, 0.f, 0.f};

    const int row_base = (s * 16 + c15) * 256;
    const int m7 = c15 & 7;
    #pragma unroll 2
    for (int kt = 0; kt < 8; kt++) {
        const int g7 = (((kt & 1) << 2) | q) ^ m7;
        bf16x8 af = *(const bf16x8*)&H[row_base + ((kt >> 1) << 6) + (g7 << 3)];
        #pragma unroll
        for (int nt = 0; nt < 8; nt++) {
            bf16x8 bv = *(const bf16x8*)&wBf[(kt * 8 + nt) * 512 + lane * 8];
            acc[nt] = __builtin_amdgcn_mfma_f32_16x16x32_bf16(af, bv, acc[nt], 0, 0, 0);
        }
    }

    // ---- wave-local RMS over the 128 channels of this scale (rows m = q*4+r) ----
    float rinv_[4];
    #pragma unroll
    for (int r = 0; r < 4; r++) {
        float ss = 0.f;
        #pragma unroll
        for (int nt = 0; nt < 8; nt++) ss += acc[nt][r] * acc[nt][r];
        ss += __shfl_xor(ss, 1);
        ss += __shfl_xor(ss, 2);
        ss += __shfl_xor(ss, 4);
        ss += __shfl_xor(ss, 8);
        rinv_[r] = 1.0f / (sqrtf(ss * (1.0f / 128.0f)) + EPSF);
    }

    const float* cn = (s == 0) ? cn1 : (s == 1) ? cn3 : (s == 2) ? cn5 : cn7;
    float cnv[8];
    #pragma unroll
    for (int nt = 0; nt < 8; nt++) cnv[nt] = cn[nt * 16 + c15];

    __syncthreads();   // all GEMM reads of H complete before F overlay

    u16* F = H;        // [16][520] bf16 feats tile
    #pragma unroll
    for (int nt = 0; nt < 8; nt++)
        #pragma unroll
        for (int r = 0; r < 4; r++) {
            const int m = q * 4 + r;
            float g = gelu_exact(acc[nt][r] * rinv_[r] * cnv[nt]);
            F[m * 520 + s * 128 + nt * 16 + c15] = f2bf(g);
        }
    __syncthreads();

    // ---- attention GEMM1: a1 = F[16,512] @ w1[128,512]^T (w1 fragment-ordered) ----
    f32x4 a1[2];
    a1[0] = f32x4{0.f, 0.f, 0.f, 0.f};
    a1[1] = f32x4{0.f, 0.f, 0.f, 0.f};
    #pragma unroll 4
    for (int kt = 0; kt < 16; kt++) {
        bf16x8 av = *(const bf16x8*)&F[c15 * 520 + kt * 32 + q * 8];
        bf16x8 bv0 = *(const bf16x8*)&w1b[(kt * 8 + wave * 2) * 512 + lane * 8];
        bf16x8 bv1 = *(const bf16x8*)&w1b[(kt * 8 + wave * 2 + 1) * 512 + lane * 8];
        a1[0] = __builtin_amdgcn_mfma_f32_16x16x32_bf16(av, bv0, a1[0], 0, 0, 0);
        a1[1] = __builtin_amdgcn_mfma_f32_16x16x32_bf16(av, bv1, a1[1], 0, 0, 0);
    }
    {
        const float b1v0 = b1[wave * 32 + c15];
        const float b1v1 = b1[wave * 32 + 16 + c15];
        #pragma unroll
        for (int r = 0; r < 4; r++) {
            a1[0][r] = gelu_exact(a1[0][r] + b1v0);
            a1[1][r] = gelu_exact(a1[1][r] + b1v1);
        }
    }

    // ---- GEMM2 partials over this wave's 32 o-channels + cross-wave softmax ----
    float w2v[4][2];
    #pragma unroll
    for (int sc = 0; sc < 4; sc++) {
        w2v[sc][0] = w2[sc * 128 + wave * 32 + c15];
        w2v[sc][1] = w2[sc * 128 + wave * 32 + 16 + c15];
    }
    #pragma unroll
    for (int r = 0; r < 4; r++) {
        float g0 = a1[0][r], g1 = a1[1][r];
        float p0 = g0 * w2v[0][0] + g1 * w2v[0][1];
        float p1 = g0 * w2v[1][0] + g1 * w2v[1][1];
        float p2 = g0 * w2v[2][0] + g1 * w2v[2][1];
        float p3 = g0 * w2v[3][0] + g1 * w2v[3][1];
        #pragma unroll
        for (int msk = 1; msk < 16; msk <<= 1) {
            p0 += __shfl_xor(p0, msk);
            p1 += __shfl_xor(p1, msk);
            p2 += __shfl_xor(p2, msk);
            p3 += __shfl_xor(p3, msk);
        }
        if (c15 == 0) {
            const int m = q * 4 + r;
            part[wave][m][0] = p0; part[wave][m][1] = p1;
            part[wave][m][2] = p2; part[wave][m][3] = p3;
        }
    }
    __syncthreads();

    if (t < 64) {
        const int m = t >> 2, sc = t & 3;
        float tot = part[0][m][sc] + part[1][m][sc] + part[2][m][sc] + part[3][m][sc] + b2[sc];
        float mx = fmaxf(tot, __shfl_xor(tot, 1));
        mx = fmaxf(mx, __shfl_xor(mx, 2));
        float e = __expf(tot - mx);
        float sum = e + __shfl_xor(e, 1);
        sum += __shfl_xor(sum, 2);
        att4[m][sc] = e * __builtin_amdgcn_rcpf(sum);
    }
    __syncthreads();

    // ---- scale by att and store (lane = 16B unit; 1 KB contiguous per row per wave) ----
    const size_t row0 = (size_t)b * 4096 + l0;
    #pragma unroll
    for (int it = 0; it < 4; it++) {
        const int r4 = it * 4 + wave;
        const float a = att4[r4][lane >> 4];
        uint4 v = *(const uint4*)&F[r4 * 520 + lane * 8];
        u32 o0 = (u32)f2bf(bf2f((u16)(v.x & 0xffffu)) * a) | ((u32)f2bf(bf2f((u16)(v.x >> 16)) * a) << 16);
        u32 o1 = (u32)f2bf(bf2f((u16)(v.y & 0xffffu)) * a) | ((u32)f2bf(bf2f((u16)(v.y >> 16)) * a) << 16);
        u32 o2 = (u32)f2bf(bf2f((u16)(v.z & 0xffffu)) * a) | ((u32)f2bf(bf2f((u16)(v.z >> 16)) * a) << 16);
        u32 o3 = (u32)f2bf(bf2f((u16)(v.w & 0xffffu)) * a) | ((u32)f2bf(bf2f((u16)(v.w >> 16)) * a) << 16);
        *(uint4*)&feats32[(row0 + r4) * 256 + lane * 4] = make_uint4(o0, o1, o2, o3);
    }
}

// ---------------- K2: ONE pack kernel for all weight panels (frag-ordered bf16) ----------
// [0, 393216)           : wbf  [24 kt][32 nchunk][512]  from fw||rw
// [393216, 524288)      : pwb  [4][8 kt][8 nt][512]     from pw1/3/5/7
// [524288, 589824)      : w1b  [16 kt][8 nt][512]       from w1
__global__ __launch_bounds__(256) void k_pack(
    const float* __restrict__ fw, const float* __restrict__ rw,
    const float* __restrict__ pw1, const float* __restrict__ pw3,
    const float* __restrict__ pw5, const float* __restrict__ pw7,
    const float* __restrict__ w1,
    u16* __restrict__ wbf, u16* __restrict__ pwb, u16* __restrict__ w1b)
{
    const u32 idx = blockIdx.x * 256 + threadIdx.x;
    if (idx < 393216u) {
        const int n = idx / 768, k = idx - n * 768;
        float v = (k < 512) ? fw[(size_t)n * 512 + k] : rw[(size_t)n * 256 + (k - 512)];
        const int kt = k >> 5, q = (k >> 3) & 3, j = k & 7;
        const int nw = n >> 7, ni = (n >> 4) & 7, c15 = n & 15;
        wbf[(size_t)(kt * 32 + nw * 8 + ni) * 512 + q * 128 + c15 * 8 + j] = f2bf(v);
    } else if (idx < 524288u) {
        const u32 i2 = idx - 393216u;
        const int s = i2 >> 15;
        const int i = i2 & 32767;
        const float* pw = (s == 0) ? pw1 : (s == 1) ? pw3 : (s == 2) ? pw5 : pw7;
        const int o = i >> 8, c = i & 255;
        const int dst = ((c >> 5) * 8 + (o >> 4)) * 512 + ((c >> 3) & 3) * 128 + (o & 15) * 8 + (c & 7);
        pwb[(size_t)s * 32768 + dst] = f2bf(pw[i]);
    } else {
        const u32 i = idx - 524288u;
        const int o = i >> 9, c = i & 511;
        const int dst = ((c >> 5) * 8 + (o >> 4)) * 512 + ((c >> 3) & 3) * 128 + (o & 15) * 8 + (c & 7);
        w1b[dst] = f2bf(w1[i]);
    }
}

// ---------------- K3 (latency-tuned): out = rmsnorm( A[65536,768] @ W[512,768]^T ) --------
// 32 rows/block, 256 threads (4 waves; wave = n-quarter, M=32 x N=128 each). LDS: Fa 32KB +
// Xa 16KB + part 0.5KB -> 3 blocks/CU (12 waves = 3/SIMD). Barrier-free fully-unrolled
// K-loop with 2-deep NAMED register double-buffer (bvA/bvB) for the 8 B-fragments: each
// fragment has a full MFMA phase (~16 MFMA) between its L2 load and its use.
__global__ __launch_bounds__(256) void k_final_norm(
    const u16* __restrict__ feats, const float* __restrict__ x,
    const u16* __restrict__ wbf, const float* __restrict__ nsc,
    float* __restrict__ out)
{
    __shared__ __align__(16) u16 Fa[32 * 512];   // 32 KB, unit-swizzled (u ^= row&15)
    __shared__ __align__(16) u16 Xa[32 * 256];   // 16 KB, unit-swizzled
    __shared__ float part[32][4];
    const int t = threadIdx.x;
    const int lane = t & 63;
    const int wave = t >> 6;          // n-quarter 0..3
    const int c15 = lane & 15;
    const int q = lane >> 4;
    const int m0 = blockIdx.x * 32;

    // ---- stage feats[32][512] -> Fa (linear dest, inverse-swizzled source) ----
    #pragma unroll
    for (int i = 0; i < 8; i++) {
        const int r = i * 4 + wave;
        gld_lds16(feats + (size_t)(m0 + r) * 512 + (size_t)((lane ^ (r & 15)) * 8),
                  &Fa[r * 512]);
    }
    // ---- stage x[32][256] -> bf16 Xa (swizzled ds_write) ----
    {
        const int r = t >> 3, sub = t & 7;
        const float4* xp = (const float4*)(x + (size_t)(m0 + r) * 256 + sub * 32);
        #pragma unroll
        for (int uu = 0; uu < 4; uu++) {
            float4 v0 = xp[2 * uu], v1 = xp[2 * uu + 1];
            u32 p0 = (u32)f2bf(v0.x) | ((u32)f2bf(v0.y) << 16);
            u32 p1 = (u32)f2bf(v0.z) | ((u32)f2bf(v0.w) << 16);
            u32 p2 = (u32)f2bf(v1.x) | ((u32)f2bf(v1.y) << 16);
            u32 p3 = (u32)f2bf(v1.z) | ((u32)f2bf(v1.w) << 16);
            const int u = (sub * 4 + uu) ^ (r & 15);
            *(uint4*)&Xa[r * 256 + u * 8] = make_uint4(p0, p1, p2, p3);
        }
    }
    __syncthreads();   // the ONLY pre-epilogue barrier

    f32x4 acc[2][8];
    #pragma unroll
    for (int i = 0; i < 2; i++)
        #pragma unroll
        for (int j = 0; j < 8; j++) acc[i][j] = f32x4{0.f, 0.f, 0.f, 0.f};

    const int ra0 = c15;
    const int ra1 = 16 + c15;
    const u16* wp = wbf + (size_t)(wave * 8) * 512 + (size_t)lane * 8;

#define LOAD_B(dst, kt)                                                        \
    _Pragma("unroll")                                                          \
    for (int ni = 0; ni < 8; ni++)                                             \
        dst[ni] = *(const bf16x8*)(wp + ((size_t)(kt) * 32 + ni) * 512);

#define COMPUTE(kt, bv)                                                        \
    {                                                                          \
        bf16x8 af0, af1;                                                       \
        if ((kt) < 16) {                                                       \
            const int u = ((kt) * 4 + q) ^ c15;                                \
            af0 = *(const bf16x8*)&Fa[ra0 * 512 + u * 8];                      \
            af1 = *(const bf16x8*)&Fa[ra1 * 512 + u * 8];                      \
        } else {                                                               \
            const int u = (((kt) - 16) * 4 + q) ^ c15;                         \
            af0 = *(const bf16x8*)&Xa[ra0 * 256 + u * 8];                      \
            af1 = *(const bf16x8*)&Xa[ra1 * 256 + u * 8];                      \
        }                                                                      \
        _Pragma("unroll")                                                      \
        for (int ni = 0; ni < 8; ni++) {                                       \
            acc[0][ni] = __builtin_amdgcn_mfma_f32_16x16x32_bf16(              \
                af0, bv[ni], acc[0][ni], 0, 0, 0);                             \
            acc[1][ni] = __builtin_amdgcn_mfma_f32_16x16x32_bf16(              \
                af1, bv[ni], acc[1][ni], 0, 0, 0);                             \
        }                                                                      \
    }

    bf16x8 bvA[8], bvB[8];
    LOAD_B(bvA, 0);
    #pragma unroll
    for (int kt2 = 0; kt2 < 12; kt2++) {
        const int k0 = kt2 * 2;
        LOAD_B(bvB, k0 + 1);
        COMPUTE(k0, bvA);
        if (kt2 < 11) { LOAD_B(bvA, k0 + 2); }
        COMPUTE(k0 + 1, bvB);
    }
#undef LOAD_B
#undef COMPUTE

    // ---- epilogue: row sum-of-squares across 4 n-waves -> rinv, *nsc, fp32 store ----
    #pragma unroll
    for (int mt = 0; mt < 2; mt++)
        #pragma unroll
        for (int r = 0; r < 4; r++) {
            float ss = 0.f;
            #pragma unroll
            for (int ni = 0; ni < 8; ni++) ss += acc[mt][ni][r] * acc[mt][ni][r];
            ss += __shfl_xor(ss, 1);
            ss += __shfl_xor(ss, 2);
            ss += __shfl_xor(ss, 4);
            ss += __shfl_xor(ss, 8);
            if (c15 == 0) part[mt * 16 + q * 4 + r][wave] = ss;
        }
    __syncthreads();

    float nscv[8];
    #pragma unroll
    for (int ni = 0; ni < 8; ni++) nscv[ni] = nsc[wave * 128 + ni * 16 + c15];

    #pragma unroll
    for (int mt = 0; mt < 2; mt++) {
        #pragma unroll
        for (int r = 0; r < 4; r++) {
            const int row = mt * 16 + q * 4 + r;
            float tot = part[row][0] + part[row][1] + part[row][2] + part[row][3];
            float rv = 1.0f / (sqrtf(tot * (1.0f / 512.0f)) + EPSF);
            float* orow = out + (size_t)(m0 + row) * 512 + wave * 128 + c15;
            #pragma unroll
            for (int ni = 0; ni < 8; ni++)
                orow[ni * 16] = acc[mt][ni][r] * rv * nscv[ni];
        }
    }
}

extern "C" void kernel_launch(void* const* d_in, const int* in_sizes, int n_in,
                              void* d_out, int out_size, void* d_ws, size_t ws_size,
                              hipStream_t stream)
{
    const float* x   = (const float*)d_in[0];
    const float* dw1 = (const float*)d_in[1];
    const float* pw1 = (const float*)d_in[2];
    const float* cn1 = (const float*)d_in[3];
    const float* dw3 = (const float*)d_in[4];
    const float* pw3 = (const float*)d_in[5];
    const float* cn3 = (const float*)d_in[6];
    const float* dw5 = (const float*)d_in[7];
    const float* pw5 = (const float*)d_in[8];
    const float* cn5 = (const float*)d_in[9];
    const float* dw7 = (const float*)d_in[10];
    const float* pw7 = (const float*)d_in[11];
    const float* cn7 = (const float*)d_in[12];
    const float* w1  = (const float*)d_in[13];
    const float* b1  = (const float*)d_in[14];
    const float* w2  = (const float*)d_in[15];
    const float* b2  = (const float*)d_in[16];
    const float* fw  = (const float*)d_in[17];
    const float* nsc = (const float*)d_in[18];
    const float* rw  = (const float*)d_in[19];

    // ws: feats bf16 [65536][512] @0 (64MB) | wbf frag-ordered (768KB) | pwb frag-ordered (256KB)
    // w1b bf16 frag-ordered (128KB) lives in the HEAD OF d_out (dead until k_final_norm overwrites it)
    u16* feats = (u16*)d_ws;
    u16* wbf   = (u16*)((char*)d_ws + (size_t)67108864);
    u16* pwb   = (u16*)((char*)d_ws + (size_t)67895296);
    u16* w1b   = (u16*)d_out;
    float* out = (float*)d_out;
    if (ws_size < (size_t)68157440) return;  // loud failure if scratch too small

    k_pack<<<dim3(2304), 256, 0, stream>>>(fw, rw, pw1, pw3, pw5, pw7, w1,
                                           wbf, pwb, w1b);
    k_feats<<<dim3(256, 16), 256, 0, stream>>>(x, dw1, dw3, dw5, dw7,
                                               cn1, cn3, cn5, cn7, pwb, w1b,
                                               b1, w2, b2, (u32*)feats);
    k_final_norm<<<dim3(2048), 256, 0, stream>>>(feats, x, wbf, nsc, out);
}